// Round 1
// baseline (553.676 us; speedup 1.0000x reference)
//
#include <hip/hip_runtime.h>
#include <stdint.h>

#define HH 10
#define DD 64
#define LL 4096
#define CC 640
#define KVL 8192
#define ALPHA 0.42f

typedef __attribute__((ext_vector_type(8))) short s16x8;
typedef __attribute__((ext_vector_type(4))) float f32x4;

__device__ inline ushort f2bf(float f) {
  uint32_t u = __builtin_bit_cast(uint32_t, f);
  u += 0x7FFFu + ((u >> 16) & 1u);   // RNE
  return (ushort)(u >> 16);
}

// ---------------- prep: hs fp32 -> bf16 ----------------
__global__ void k_cvt_hs(const float* __restrict__ in, ushort* __restrict__ out, int n4) {
  int i = blockIdx.x * blockDim.x + threadIdx.x;
  if (i < n4) {
    float4 v = ((const float4*)in)[i];
    ushort4 o;
    o.x = f2bf(v.x); o.y = f2bf(v.y); o.z = f2bf(v.z); o.w = f2bf(v.w);
    ((ushort4*)out)[i] = o;
  }
}

// ---------------- prep: W [K][N] fp32 -> WT [N][K] bf16 ----------------
__global__ void k_wT(const float* __restrict__ W, ushort* __restrict__ WT) {
  __shared__ ushort t[64][65];
  int k0 = blockIdx.x * 64, n0 = blockIdx.y * 64;
  int tid = threadIdx.x;
#pragma unroll
  for (int i = 0; i < 4; ++i) {
    int id = tid + i * 256;
    int r = id >> 4, c4 = id & 15;
    float4 v = *(const float4*)(W + (size_t)(k0 + r) * CC + n0 + c4 * 4);
    t[r][c4 * 4 + 0] = f2bf(v.x);
    t[r][c4 * 4 + 1] = f2bf(v.y);
    t[r][c4 * 4 + 2] = f2bf(v.z);
    t[r][c4 * 4 + 3] = f2bf(v.w);
  }
  __syncthreads();
#pragma unroll
  for (int i = 0; i < 2; ++i) {
    int id = tid + i * 256;
    int n = id >> 3, cc = id & 7;
    ushort tmp[8];
#pragma unroll
    for (int j = 0; j < 8; ++j) tmp[j] = t[cc * 8 + j][n];
    *(uint4*)(WT + (size_t)(n0 + n) * CC + k0 + cc * 8) = *(uint4*)tmp;
  }
}

// ---------------- prep: background KV -> alpha-scaled bf16 at rows L.. ----------------
__global__ void k_cvt_bg(const float* __restrict__ Kbg, const float* __restrict__ Vbg,
                         ushort* __restrict__ kb, ushort* __restrict__ vb, int n4) {
  int i = blockIdx.x * blockDim.x + threadIdx.x;
  if (i >= n4) return;
  int e = i * 4;
  int h = e / (LL * DD);
  int rem = e - h * (LL * DD);
  size_t dst = (size_t)h * KVL * DD + (size_t)LL * DD + rem;
  float4 kv = ((const float4*)Kbg)[i];
  float4 vv = ((const float4*)Vbg)[i];
  ushort4 ok, ov;
  ok.x = f2bf(ALPHA * kv.x); ok.y = f2bf(ALPHA * kv.y);
  ok.z = f2bf(ALPHA * kv.z); ok.w = f2bf(ALPHA * kv.w);
  ov.x = f2bf(ALPHA * vv.x); ov.y = f2bf(ALPHA * vv.y);
  ov.z = f2bf(ALPHA * vv.z); ov.w = f2bf(ALPHA * vv.w);
  *(ushort4*)(kb + dst) = ok;
  *(ushort4*)(vb + dst) = ov;
}

// ---------------- bf16 GEMM: C[M][N] = A[M][K] * BT[N][K]^T ----------------
// BM=128 BN=64 BK=64, 512 threads = 8 waves (4 x 2 of 32x32)
template <bool FP32OUT>
__global__ __launch_bounds__(512) void k_gemm(
    const ushort* __restrict__ A, const ushort* __restrict__ BT,
    ushort* __restrict__ outB, float* __restrict__ outF,
    const float* __restrict__ bias, int M, int Kd, int N, size_t headStride) {
  __shared__ uint4 As4[128 * 8];
  __shared__ uint4 Bs4[64 * 8];
  int tid = threadIdx.x;
  int m0 = blockIdx.x * 128, n0 = blockIdx.y * 64;
  int wid = tid >> 6, lane = tid & 63;
  int wr = wid >> 1, wc = wid & 1;
  int lr = lane & 15, lg = lane >> 4;
  f32x4 acc[2][2] = {};

  for (int kt = 0; kt < Kd; kt += 64) {
    __syncthreads();
    {
      int id = tid;
#pragma unroll
      for (int i = 0; i < 2; ++i, id += 512) {
        int r = id >> 3, cc = id & 7;
        uint4 v = *(const uint4*)(A + (size_t)(m0 + r) * Kd + kt + cc * 8);
        As4[r * 8 + (cc ^ (r & 7))] = v;
      }
      int r = tid >> 3, cc = tid & 7;
      uint4 v = *(const uint4*)(BT + (size_t)(n0 + r) * Kd + kt + cc * 8);
      Bs4[r * 8 + (cc ^ (r & 7))] = v;
    }
    __syncthreads();
#pragma unroll
    for (int k0 = 0; k0 < 2; ++k0) {
      s16x8 a[2], b[2];
#pragma unroll
      for (int i = 0; i < 2; ++i) {
        int r = wr * 32 + i * 16 + lr;
        a[i] = *(const s16x8*)&As4[r * 8 + ((k0 * 4 + lg) ^ (r & 7))];
      }
#pragma unroll
      for (int j = 0; j < 2; ++j) {
        int r = wc * 32 + j * 16 + lr;
        b[j] = *(const s16x8*)&Bs4[r * 8 + ((k0 * 4 + lg) ^ (r & 7))];
      }
#pragma unroll
      for (int i = 0; i < 2; ++i)
#pragma unroll
        for (int j = 0; j < 2; ++j)
          acc[i][j] = __builtin_amdgcn_mfma_f32_16x16x32_bf16(a[i], b[j], acc[i][j], 0, 0, 0);
    }
  }
#pragma unroll
  for (int i = 0; i < 2; ++i)
#pragma unroll
    for (int j = 0; j < 2; ++j)
#pragma unroll
      for (int q = 0; q < 4; ++q) {
        int m = m0 + wr * 32 + i * 16 + lg * 4 + q;
        int n = n0 + wc * 32 + j * 16 + lr;
        float v = acc[i][j][q];
        if (FP32OUT) {
          outF[(size_t)m * N + n] = v + bias[n];
        } else {
          size_t idx = (size_t)(n >> 6) * headStride + (size_t)m * 64 + (n & 63);
          outB[idx] = f2bf(v);
        }
      }
}

// ---------------- flash attention ----------------
// grid (L/128, H), 512 threads = 8 waves, each wave owns 16 q-rows. KVBLK=64.
__global__ __launch_bounds__(512) void k_attn(
    const ushort* __restrict__ qb,   // [H][L][D]
    const ushort* __restrict__ kb,   // [H][KVL][D]
    const ushort* __restrict__ vb,   // [H][KVL][D]
    ushort* __restrict__ ctx) {      // [L][C]
  __shared__ uint4 Ks4[64 * 8];          // K tile [kv][d], swizzled
  __shared__ uint4 Vs4[64 * 8];          // V^T tile [d][kv], swizzled
  __shared__ ushort Ps[8][16 * 64];      // per-wave P tile, swizzled

  int tid = threadIdx.x, wid = tid >> 6, lane = tid & 63;
  int lr = lane & 15, lg = lane >> 4;
  int h = blockIdx.y;
  int q0 = blockIdx.x * 128 + wid * 16;

  const ushort* qptr = qb + ((size_t)h * LL + q0 + lr) * DD + lg * 8;
  s16x8 qa0 = *(const s16x8*)qptr;
  s16x8 qa1 = *(const s16x8*)(qptr + 32);

  f32x4 o[4] = {};
  float m[4], l[4];
#pragma unroll
  for (int q = 0; q < 4; ++q) { m[q] = -1e30f; l[q] = 0.f; }
  const float sc2 = 0.125f * 1.44269504089f;  // (1/sqrt(D)) * log2(e)

  const ushort* kbh = kb + (size_t)h * KVL * DD;
  const ushort* vbh = vb + (size_t)h * KVL * DD;
  ushort* Pw = Ps[wid];
  ushort* Vs = (ushort*)Vs4;

  for (int kv0 = 0; kv0 < KVL; kv0 += 64) {
    __syncthreads();
    {  // stage K tile: [kv][d] bf16, one 16B chunk per thread
      int r = tid >> 3, cc = tid & 7;
      uint4 v = *(const uint4*)(kbh + (size_t)(kv0 + r) * DD + cc * 8);
      Ks4[r * 8 + (cc ^ (r & 7))] = v;
    }
    if (tid < 256) {  // stage V^T: read 2 kv-rows, write ushort2 along kv
      int rp = tid >> 3, cc = tid & 7;
      const ushort* p0 = vbh + (size_t)(kv0 + rp * 2) * DD + cc * 8;
      s16x8 v0 = *(const s16x8*)p0;
      s16x8 v1 = *(const s16x8*)(p0 + DD);
#pragma unroll
      for (int j = 0; j < 8; ++j) {
        int d = cc * 8 + j;
        int kvp = rp * 2;
        uint pack = (uint)(ushort)v0[j] | ((uint)(ushort)v1[j] << 16);
        *(uint*)&Vs[d * 64 + (kvp ^ ((d & 7) << 3))] = pack;
      }
    }
    __syncthreads();

    // S = Q K^T : 8 MFMA
    f32x4 s[4] = {};
#pragma unroll
    for (int k0 = 0; k0 < 2; ++k0) {
      s16x8 qa = k0 ? qa1 : qa0;
#pragma unroll
      for (int j = 0; j < 4; ++j) {
        int r = j * 16 + lr;
        s16x8 b = *(const s16x8*)&Ks4[r * 8 + ((k0 * 4 + lg) ^ (r & 7))];
        s[j] = __builtin_amdgcn_mfma_f32_16x16x32_bf16(qa, b, s[j], 0, 0, 0);
      }
    }

    // online softmax (rows = lg*4+q, cols = lr + j*16)
    float pmax[4];
#pragma unroll
    for (int q = 0; q < 4; ++q)
      pmax[q] = fmaxf(fmaxf(s[0][q], s[1][q]), fmaxf(s[2][q], s[3][q]));
#pragma unroll
    for (int off = 1; off < 16; off <<= 1)
#pragma unroll
      for (int q = 0; q < 4; ++q)
        pmax[q] = fmaxf(pmax[q], __shfl_xor(pmax[q], off));

    float fsc[4], rowsum[4], p[4][4];
#pragma unroll
    for (int q = 0; q < 4; ++q) {
      float mn = fmaxf(m[q], pmax[q] * sc2);
      fsc[q] = exp2f(m[q] - mn);
      m[q] = mn;
      float rs = 0.f;
#pragma unroll
      for (int j = 0; j < 4; ++j) {
        float pv = exp2f(s[j][q] * sc2 - mn);
        p[j][q] = pv;
        rs += pv;
      }
      rowsum[q] = rs;
    }
#pragma unroll
    for (int off = 1; off < 16; off <<= 1)
#pragma unroll
      for (int q = 0; q < 4; ++q)
        rowsum[q] += __shfl_xor(rowsum[q], off);
#pragma unroll
    for (int q = 0; q < 4; ++q) {
      l[q] = l[q] * fsc[q] + rowsum[q];
#pragma unroll
      for (int j = 0; j < 4; ++j) o[j][q] *= fsc[q];
    }

    // P -> per-wave LDS (bf16, swizzled)
#pragma unroll
    for (int j = 0; j < 4; ++j)
#pragma unroll
      for (int q = 0; q < 4; ++q) {
        int r = lg * 4 + q, c = j * 16 + lr;
        Pw[r * 64 + (c ^ ((r & 7) << 3))] = f2bf(p[j][q]);
      }
    asm volatile("s_waitcnt lgkmcnt(0)" ::: "memory");
    __builtin_amdgcn_sched_barrier(0);

    // O += P V : 8 MFMA
#pragma unroll
    for (int k0 = 0; k0 < 2; ++k0) {
      s16x8 pa = *(const s16x8*)&Pw[lr * 64 + ((k0 * 32 + lg * 8) ^ ((lr & 7) << 3))];
#pragma unroll
      for (int j = 0; j < 4; ++j) {
        int r = j * 16 + lr;  // d row in V^T
        s16x8 bv = *(const s16x8*)&Vs[r * 64 + ((k0 * 32 + lg * 8) ^ ((r & 7) << 3))];
        o[j] = __builtin_amdgcn_mfma_f32_16x16x32_bf16(pa, bv, o[j], 0, 0, 0);
      }
    }
  }

  // epilogue: ctx[q0+row][h*64 + d]
#pragma unroll
  for (int j = 0; j < 4; ++j)
#pragma unroll
    for (int q = 0; q < 4; ++q) {
      int row = q0 + lg * 4 + q;
      int col = h * 64 + j * 16 + lr;
      ctx[(size_t)row * CC + col] = f2bf(o[j][q] / l[q]);
    }
}

extern "C" void kernel_launch(void* const* d_in, const int* in_sizes, int n_in,
                              void* d_out, int out_size, void* d_ws, size_t ws_size,
                              hipStream_t stream) {
  const float* hs  = (const float*)d_in[0];
  const float* Kbg = (const float*)d_in[1];
  const float* Vbg = (const float*)d_in[2];
  const float* Wq  = (const float*)d_in[3];
  const float* Wk  = (const float*)d_in[4];
  const float* Wv  = (const float*)d_in[5];
  const float* Wo  = (const float*)d_in[6];
  const float* bo  = (const float*)d_in[7];
  float* out = (float*)d_out;

  char* p = (char*)d_ws;
  ushort* hs_b = (ushort*)p; p += (size_t)LL * CC * 2;
  ushort* WqT  = (ushort*)p; p += (size_t)CC * CC * 2;
  ushort* WkT  = (ushort*)p; p += (size_t)CC * CC * 2;
  ushort* WvT  = (ushort*)p; p += (size_t)CC * CC * 2;
  ushort* WoT  = (ushort*)p; p += (size_t)CC * CC * 2;
  ushort* qb   = (ushort*)p; p += (size_t)HH * LL * DD * 2;
  ushort* kb   = (ushort*)p; p += (size_t)HH * KVL * DD * 2;
  ushort* vb   = (ushort*)p; p += (size_t)HH * KVL * DD * 2;
  ushort* ctxb = (ushort*)p; p += (size_t)LL * CC * 2;

  int n4hs = LL * CC / 4;
  k_cvt_hs<<<(n4hs + 255) / 256, 256, 0, stream>>>(hs, hs_b, n4hs);
  k_wT<<<dim3(CC / 64, CC / 64), 256, 0, stream>>>(Wq, WqT);
  k_wT<<<dim3(CC / 64, CC / 64), 256, 0, stream>>>(Wk, WkT);
  k_wT<<<dim3(CC / 64, CC / 64), 256, 0, stream>>>(Wv, WvT);
  k_wT<<<dim3(CC / 64, CC / 64), 256, 0, stream>>>(Wo, WoT);
  int n4bg = HH * LL * DD / 4;
  k_cvt_bg<<<(n4bg + 255) / 256, 256, 0, stream>>>(Kbg, Vbg, kb, vb, n4bg);

  k_gemm<false><<<dim3(LL / 128, CC / 64), 512, 0, stream>>>(
      hs_b, WqT, qb, nullptr, nullptr, LL, CC, CC, (size_t)LL * DD);
  k_gemm<false><<<dim3(LL / 128, CC / 64), 512, 0, stream>>>(
      hs_b, WkT, kb, nullptr, nullptr, LL, CC, CC, (size_t)KVL * DD);
  k_gemm<false><<<dim3(LL / 128, CC / 64), 512, 0, stream>>>(
      hs_b, WvT, vb, nullptr, nullptr, LL, CC, CC, (size_t)KVL * DD);

  k_attn<<<dim3(LL / 128, HH), 512, 0, stream>>>(qb, kb, vb, ctxb);

  k_gemm<true><<<dim3(LL / 128, CC / 64), 512, 0, stream>>>(
      ctxb, WoT, nullptr, out, bo, LL, CC, CC, 0);
}

// Round 2
// 448.889 us; speedup vs baseline: 1.2334x; 1.2334x over previous
//
#include <hip/hip_runtime.h>
#include <stdint.h>

#define HH 10
#define DD 64
#define LL 4096
#define CC 640
#define KVL 8192
#define ALPHA 0.42f

typedef __attribute__((ext_vector_type(8))) short s16x8;
typedef __attribute__((ext_vector_type(4))) float f32x4;

__device__ inline ushort f2bf(float f) {
  uint32_t u = __builtin_bit_cast(uint32_t, f);
  u += 0x7FFFu + ((u >> 16) & 1u);   // RNE
  return (ushort)(u >> 16);
}

__device__ inline void gl16(const ushort* g, ushort* l) {
  __builtin_amdgcn_global_load_lds(
      (const __attribute__((address_space(1))) uint32_t*)g,
      (__attribute__((address_space(3))) uint32_t*)l, 16, 0, 0);
}

__device__ inline void bar() {
  __builtin_amdgcn_sched_barrier(0);
  __builtin_amdgcn_s_barrier();
  __builtin_amdgcn_sched_barrier(0);
}

// ---------------- prep: hs fp32 -> bf16 ----------------
__global__ void k_cvt_hs(const float* __restrict__ in, ushort* __restrict__ out, int n4) {
  int i = blockIdx.x * blockDim.x + threadIdx.x;
  if (i < n4) {
    float4 v = ((const float4*)in)[i];
    ushort4 o;
    o.x = f2bf(v.x); o.y = f2bf(v.y); o.z = f2bf(v.z); o.w = f2bf(v.w);
    ((ushort4*)out)[i] = o;
  }
}

// ---------------- prep: W [K][N] fp32 -> WT [N][K] bf16 ----------------
__global__ void k_wT(const float* __restrict__ W, ushort* __restrict__ WT) {
  __shared__ ushort t[64][65];
  int k0 = blockIdx.x * 64, n0 = blockIdx.y * 64;
  int tid = threadIdx.x;
#pragma unroll
  for (int i = 0; i < 4; ++i) {
    int id = tid + i * 256;
    int r = id >> 4, c4 = id & 15;
    float4 v = *(const float4*)(W + (size_t)(k0 + r) * CC + n0 + c4 * 4);
    t[r][c4 * 4 + 0] = f2bf(v.x);
    t[r][c4 * 4 + 1] = f2bf(v.y);
    t[r][c4 * 4 + 2] = f2bf(v.z);
    t[r][c4 * 4 + 3] = f2bf(v.w);
  }
  __syncthreads();
#pragma unroll
  for (int i = 0; i < 2; ++i) {
    int id = tid + i * 256;
    int n = id >> 3, cc = id & 7;
    ushort tmp[8];
#pragma unroll
    for (int j = 0; j < 8; ++j) tmp[j] = t[cc * 8 + j][n];
    *(uint4*)(WT + (size_t)(n0 + n) * CC + k0 + cc * 8) = *(uint4*)tmp;
  }
}

// ---------------- prep: background KV (rows L..KVL-1) ----------------
// K: [h][kv][64] with 16B-chunk swizzle within row (chunk ^= kv&7)
// V: transposed tiles [h][tile=kv/64][d=64][chunk=8][8kv] with chunk ^= d&7
__global__ void k_cvt_bg(const float* __restrict__ Kbg, const float* __restrict__ Vbg,
                         ushort* __restrict__ kb, ushort* __restrict__ vbT, int n4) {
  int i = blockIdx.x * blockDim.x + threadIdx.x;
  if (i >= n4) return;
  int e = i * 4;
  int h = e / (LL * DD);
  int rem = e - h * (LL * DD);
  int kvl = rem >> 6;        // local row 0..4095
  int d0 = rem & 63;         // multiple of 4
  int kv = LL + kvl;         // global kv row
  float4 kf = ((const float4*)Kbg)[i];
  float4 vf = ((const float4*)Vbg)[i];
  // K write (ushort4, swizzled chunk)
  {
    int chunk = d0 >> 3, off = d0 & 7;
    size_t kdst = ((size_t)h * KVL + kv) * 64 + (size_t)(((chunk ^ (kv & 7)) << 3) + off);
    ushort4 ok;
    ok.x = f2bf(ALPHA * kf.x); ok.y = f2bf(ALPHA * kf.y);
    ok.z = f2bf(ALPHA * kf.z); ok.w = f2bf(ALPHA * kf.w);
    *(ushort4*)(kb + kdst) = ok;
  }
  // V^T write (4 scalar ushorts)
  {
    int tile = kv >> 6, kl = kv & 63;
    size_t vbase = ((size_t)h * 128 + tile) * 4096;
    float vv[4] = {vf.x, vf.y, vf.z, vf.w};
#pragma unroll
    for (int j = 0; j < 4; ++j) {
      int d = d0 + j;
      vbT[vbase + d * 64 + (((kl >> 3) ^ (d & 7)) << 3) + (kl & 7)] = f2bf(ALPHA * vv[j]);
    }
  }
}

// ---------------- bf16 GEMM: C[M][N] = A[M][K] * BT[N][K]^T ----------------
// MODE 0: bf16 head layout plain (Q)   MODE 1: K row-swizzled
// MODE 2: V transposed+swizzled tiles  MODE 3: fp32 + bias (final)
template <int MODE>
__global__ __launch_bounds__(512) void k_gemm(
    const ushort* __restrict__ A, const ushort* __restrict__ BT,
    ushort* __restrict__ outB, float* __restrict__ outF,
    const float* __restrict__ bias, int M, int Kd, int N, size_t headStride) {
  __shared__ uint4 As4[128 * 8];
  __shared__ uint4 Bs4[64 * 8];
  int tid = threadIdx.x;
  int m0 = blockIdx.x * 128, n0 = blockIdx.y * 64;
  int wid = tid >> 6, lane = tid & 63;
  int wr = wid >> 1, wc = wid & 1;
  int lr = lane & 15, lg = lane >> 4;
  f32x4 acc[2][2] = {};

  for (int kt = 0; kt < Kd; kt += 64) {
    __syncthreads();
    {
      int id = tid;
#pragma unroll
      for (int i = 0; i < 2; ++i, id += 512) {
        int r = id >> 3, cc = id & 7;
        uint4 v = *(const uint4*)(A + (size_t)(m0 + r) * Kd + kt + cc * 8);
        As4[r * 8 + (cc ^ (r & 7))] = v;
      }
      int r = tid >> 3, cc = tid & 7;
      uint4 v = *(const uint4*)(BT + (size_t)(n0 + r) * Kd + kt + cc * 8);
      Bs4[r * 8 + (cc ^ (r & 7))] = v;
    }
    __syncthreads();
#pragma unroll
    for (int k0 = 0; k0 < 2; ++k0) {
      s16x8 a[2], b[2];
#pragma unroll
      for (int i = 0; i < 2; ++i) {
        int r = wr * 32 + i * 16 + lr;
        a[i] = *(const s16x8*)&As4[r * 8 + ((k0 * 4 + lg) ^ (r & 7))];
      }
#pragma unroll
      for (int j = 0; j < 2; ++j) {
        int r = wc * 32 + j * 16 + lr;
        b[j] = *(const s16x8*)&Bs4[r * 8 + ((k0 * 4 + lg) ^ (r & 7))];
      }
#pragma unroll
      for (int i = 0; i < 2; ++i)
#pragma unroll
        for (int j = 0; j < 2; ++j)
          acc[i][j] = __builtin_amdgcn_mfma_f32_16x16x32_bf16(a[i], b[j], acc[i][j], 0, 0, 0);
    }
  }
#pragma unroll
  for (int i = 0; i < 2; ++i)
#pragma unroll
    for (int j = 0; j < 2; ++j)
#pragma unroll
      for (int q = 0; q < 4; ++q) {
        int m = m0 + wr * 32 + i * 16 + lg * 4 + q;
        int n = n0 + wc * 32 + j * 16 + lr;
        float v = acc[i][j][q];
        if (MODE == 3) {
          outF[(size_t)m * N + n] = v + bias[n];
        } else if (MODE == 0) {
          outB[(size_t)(n >> 6) * headStride + (size_t)m * 64 + (n & 63)] = f2bf(v);
        } else if (MODE == 1) {
          int d = n & 63;
          outB[(size_t)(n >> 6) * headStride + (size_t)m * 64 +
               (((d >> 3) ^ (m & 7)) << 3) + (d & 7)] = f2bf(v);
        } else {  // MODE 2: V^T tiles
          int d = n & 63, tile = m >> 6, kl = m & 63;
          outB[((size_t)(n >> 6) * 128 + tile) * 4096 + (size_t)d * 64 +
               (((kl >> 3) ^ (d & 7)) << 3) + (kl & 7)] = f2bf(v);
        }
      }
}

// ---------------- flash attention ----------------
// grid (L/64, H), 256 threads = 4 waves, each wave owns 16 q-rows. KVBLK=64.
// K/V^T staged via global_load_lds (pre-swizzled global), double-buffered,
// counted vmcnt + raw barriers (no drain in main loop).
__global__ __launch_bounds__(256) void k_attn(
    const ushort* __restrict__ qb,    // [H][L][64]
    const ushort* __restrict__ kb,    // [H][KVL][64] row-swizzled
    const ushort* __restrict__ vbT,   // [H][128][4096] V^T tiles, swizzled
    ushort* __restrict__ ctx) {       // [L][C]
  __shared__ ushort Ks[2][4096];
  __shared__ ushort Vs[2][4096];
  __shared__ ushort Ps[4][1024];

  int tid = threadIdx.x, wid = tid >> 6, lane = tid & 63;
  int lr = lane & 15, lg = lane >> 4;
  int h = blockIdx.y;
  int q0 = blockIdx.x * 64 + wid * 16;

  const ushort* qptr = qb + ((size_t)h * LL + q0 + lr) * DD + lg * 8;
  s16x8 qa0 = *(const s16x8*)qptr;
  s16x8 qa1 = *(const s16x8*)(qptr + 32);

  f32x4 o[4] = {};
  float m[4], l[4];
#pragma unroll
  for (int q = 0; q < 4; ++q) { m[q] = -1e30f; l[q] = 0.f; }
  const float sc2 = 0.125f * 1.44269504089f;  // (1/sqrt(D)) * log2(e)

  const ushort* kh = kb + (size_t)h * KVL * DD;
  const ushort* vh = vbT + (size_t)h * 128 * 4096;
  ushort* Pw = Ps[wid];

  int cur = 0;
  // stage tile 0
  {
    const ushort* gk = kh;
    const ushort* gv = vh;
#pragma unroll
    for (int i = 0; i < 2; ++i) {
      gl16(gk + (i * 256 + tid) * 8, &Ks[0][i * 2048 + wid * 512]);
      gl16(gv + (i * 256 + tid) * 8, &Vs[0][i * 2048 + wid * 512]);
    }
  }

  for (int t = 0; t < KVL / 64; ++t) {
    if (t < KVL / 64 - 1) {
      const ushort* gk = kh + (size_t)(t + 1) * 4096;
      const ushort* gv = vh + (size_t)(t + 1) * 4096;
      int nb = cur ^ 1;
#pragma unroll
      for (int i = 0; i < 2; ++i) {
        gl16(gk + (i * 256 + tid) * 8, &Ks[nb][i * 2048 + wid * 512]);
        gl16(gv + (i * 256 + tid) * 8, &Vs[nb][i * 2048 + wid * 512]);
      }
      asm volatile("s_waitcnt vmcnt(4)" ::: "memory");
    } else {
      asm volatile("s_waitcnt vmcnt(0)" ::: "memory");
    }
    bar();

    const ushort* Kc = Ks[cur];
    const ushort* Vc = Vs[cur];

    // S = Q K^T : 8 MFMA
    f32x4 s[4] = {};
#pragma unroll
    for (int k0 = 0; k0 < 2; ++k0) {
      s16x8 qa = k0 ? qa1 : qa0;
#pragma unroll
      for (int j = 0; j < 4; ++j) {
        int r = j * 16 + lr;
        s16x8 b = *(const s16x8*)&Kc[r * 64 + (((k0 * 4 + lg) ^ (r & 7)) << 3)];
        s[j] = __builtin_amdgcn_mfma_f32_16x16x32_bf16(qa, b, s[j], 0, 0, 0);
      }
    }

    // online softmax (rows = lg*4+q, cols = lr + j*16)
    float pmax[4];
#pragma unroll
    for (int q = 0; q < 4; ++q)
      pmax[q] = fmaxf(fmaxf(s[0][q], s[1][q]), fmaxf(s[2][q], s[3][q]));
#pragma unroll
    for (int off = 1; off < 16; off <<= 1)
#pragma unroll
      for (int q = 0; q < 4; ++q)
        pmax[q] = fmaxf(pmax[q], __shfl_xor(pmax[q], off));

    float fsc[4], rowsum[4], p[4][4];
#pragma unroll
    for (int q = 0; q < 4; ++q) {
      float mn = fmaxf(m[q], pmax[q] * sc2);
      fsc[q] = exp2f(m[q] - mn);
      m[q] = mn;
      float rs = 0.f;
#pragma unroll
      for (int j = 0; j < 4; ++j) {
        float pv = exp2f(s[j][q] * sc2 - mn);
        p[j][q] = pv;
        rs += pv;
      }
      rowsum[q] = rs;
    }
#pragma unroll
    for (int off = 1; off < 16; off <<= 1)
#pragma unroll
      for (int q = 0; q < 4; ++q)
        rowsum[q] += __shfl_xor(rowsum[q], off);
#pragma unroll
    for (int q = 0; q < 4; ++q) {
      l[q] = l[q] * fsc[q] + rowsum[q];
#pragma unroll
      for (int j = 0; j < 4; ++j) o[j][q] *= fsc[q];
    }

    // P -> per-wave LDS (bf16, swizzled)
#pragma unroll
    for (int j = 0; j < 4; ++j)
#pragma unroll
      for (int q = 0; q < 4; ++q) {
        int r = lg * 4 + q, c = j * 16 + lr;
        Pw[r * 64 + (c ^ ((r & 7) << 3))] = f2bf(p[j][q]);
      }
    asm volatile("s_waitcnt lgkmcnt(0)" ::: "memory");
    __builtin_amdgcn_sched_barrier(0);

    // O += P V : 8 MFMA
#pragma unroll
    for (int k0 = 0; k0 < 2; ++k0) {
      s16x8 pa = *(const s16x8*)&Pw[lr * 64 + (((k0 * 4 + lg) ^ (lr & 7)) << 3)];
#pragma unroll
      for (int j = 0; j < 4; ++j) {
        int r = j * 16 + lr;  // d row in V^T
        s16x8 bv = *(const s16x8*)&Vc[r * 64 + (((k0 * 4 + lg) ^ (r & 7)) << 3)];
        o[j] = __builtin_amdgcn_mfma_f32_16x16x32_bf16(pa, bv, o[j], 0, 0, 0);
      }
    }
    bar();
    cur ^= 1;
  }

  // epilogue: ctx[q0+row][h*64 + d]
#pragma unroll
  for (int j = 0; j < 4; ++j)
#pragma unroll
    for (int q = 0; q < 4; ++q) {
      int row = q0 + lg * 4 + q;
      int col = h * 64 + j * 16 + lr;
      ctx[(size_t)row * CC + col] = f2bf(o[j][q] / l[q]);
    }
}

extern "C" void kernel_launch(void* const* d_in, const int* in_sizes, int n_in,
                              void* d_out, int out_size, void* d_ws, size_t ws_size,
                              hipStream_t stream) {
  const float* hs  = (const float*)d_in[0];
  const float* Kbg = (const float*)d_in[1];
  const float* Vbg = (const float*)d_in[2];
  const float* Wq  = (const float*)d_in[3];
  const float* Wk  = (const float*)d_in[4];
  const float* Wv  = (const float*)d_in[5];
  const float* Wo  = (const float*)d_in[6];
  const float* bo  = (const float*)d_in[7];
  float* out = (float*)d_out;

  char* p = (char*)d_ws;
  ushort* hs_b = (ushort*)p; p += (size_t)LL * CC * 2;
  ushort* WqT  = (ushort*)p; p += (size_t)CC * CC * 2;
  ushort* WkT  = (ushort*)p; p += (size_t)CC * CC * 2;
  ushort* WvT  = (ushort*)p; p += (size_t)CC * CC * 2;
  ushort* WoT  = (ushort*)p; p += (size_t)CC * CC * 2;
  ushort* qb   = (ushort*)p; p += (size_t)HH * LL * DD * 2;
  ushort* kb   = (ushort*)p; p += (size_t)HH * KVL * DD * 2;
  ushort* vbT  = (ushort*)p; p += (size_t)HH * KVL * DD * 2;
  ushort* ctxb = (ushort*)p; p += (size_t)LL * CC * 2;

  int n4hs = LL * CC / 4;
  k_cvt_hs<<<(n4hs + 255) / 256, 256, 0, stream>>>(hs, hs_b, n4hs);
  k_wT<<<dim3(CC / 64, CC / 64), 256, 0, stream>>>(Wq, WqT);
  k_wT<<<dim3(CC / 64, CC / 64), 256, 0, stream>>>(Wk, WkT);
  k_wT<<<dim3(CC / 64, CC / 64), 256, 0, stream>>>(Wv, WvT);
  k_wT<<<dim3(CC / 64, CC / 64), 256, 0, stream>>>(Wo, WoT);
  int n4bg = HH * LL * DD / 4;
  k_cvt_bg<<<(n4bg + 255) / 256, 256, 0, stream>>>(Kbg, Vbg, kb, vbT, n4bg);

  k_gemm<0><<<dim3(LL / 128, CC / 64), 512, 0, stream>>>(
      hs_b, WqT, qb, nullptr, nullptr, LL, CC, CC, (size_t)LL * DD);
  k_gemm<1><<<dim3(LL / 128, CC / 64), 512, 0, stream>>>(
      hs_b, WkT, kb, nullptr, nullptr, LL, CC, CC, (size_t)KVL * DD);
  k_gemm<2><<<dim3(LL / 128, CC / 64), 512, 0, stream>>>(
      hs_b, WvT, vbT, nullptr, nullptr, LL, CC, CC, 0);

  k_attn<<<dim3(LL / 64, HH), 256, 0, stream>>>(qb, kb, vbT, ctxb);

  k_gemm<3><<<dim3(LL / 128, CC / 64), 512, 0, stream>>>(
      ctxb, WoT, nullptr, out, bo, LL, CC, CC, 0);
}

// Round 3
// 309.588 us; speedup vs baseline: 1.7884x; 1.4500x over previous
//
#include <hip/hip_runtime.h>
#include <stdint.h>

#define HH 10
#define DD 64
#define LL 4096
#define CC 640
#define KVL 8192
#define ALPHA 0.42f
#define SPLIT 2

typedef __attribute__((ext_vector_type(8))) short s16x8;
typedef __attribute__((ext_vector_type(4))) float f32x4;

__device__ inline ushort f2bf(float f) {
  uint32_t u = __builtin_bit_cast(uint32_t, f);
  u += 0x7FFFu + ((u >> 16) & 1u);   // RNE
  return (ushort)(u >> 16);
}

__device__ inline uint cvtpk(float lo, float hi) {
  uint r;
  asm("v_cvt_pk_bf16_f32 %0, %1, %2" : "=v"(r) : "v"(lo), "v"(hi));
  return r;
}

__device__ inline void gl16(const ushort* g, ushort* l) {
  __builtin_amdgcn_global_load_lds(
      (const __attribute__((address_space(1))) uint32_t*)g,
      (__attribute__((address_space(3))) uint32_t*)l, 16, 0, 0);
}

__device__ inline void bar() {
  __builtin_amdgcn_sched_barrier(0);
  __builtin_amdgcn_s_barrier();
  __builtin_amdgcn_sched_barrier(0);
}

// V^T tile column position for kv-local row kl (0..63):
// position p holds kv label (p&3)*16 + (p>>2); inverse: p = (kl&15)*4 + (kl>>4)
__device__ inline int vpos(int kl) { return ((kl & 15) << 2) | (kl >> 4); }

// ---------------- prep: hs fp32 -> bf16 ----------------
__global__ void k_cvt_hs(const float* __restrict__ in, ushort* __restrict__ out, int n4) {
  int i = blockIdx.x * blockDim.x + threadIdx.x;
  if (i < n4) {
    float4 v = ((const float4*)in)[i];
    ushort4 o;
    o.x = f2bf(v.x); o.y = f2bf(v.y); o.z = f2bf(v.z); o.w = f2bf(v.w);
    ((ushort4*)out)[i] = o;
  }
}

// ---------------- prep: W [K][N] fp32 -> WT [N][K] bf16 ----------------
__global__ void k_wT(const float* __restrict__ W, ushort* __restrict__ WT) {
  __shared__ ushort t[64][65];
  int k0 = blockIdx.x * 64, n0 = blockIdx.y * 64;
  int tid = threadIdx.x;
#pragma unroll
  for (int i = 0; i < 4; ++i) {
    int id = tid + i * 256;
    int r = id >> 4, c4 = id & 15;
    float4 v = *(const float4*)(W + (size_t)(k0 + r) * CC + n0 + c4 * 4);
    t[r][c4 * 4 + 0] = f2bf(v.x);
    t[r][c4 * 4 + 1] = f2bf(v.y);
    t[r][c4 * 4 + 2] = f2bf(v.z);
    t[r][c4 * 4 + 3] = f2bf(v.w);
  }
  __syncthreads();
#pragma unroll
  for (int i = 0; i < 2; ++i) {
    int id = tid + i * 256;
    int n = id >> 3, cc = id & 7;
    ushort tmp[8];
#pragma unroll
    for (int j = 0; j < 8; ++j) tmp[j] = t[cc * 8 + j][n];
    *(uint4*)(WT + (size_t)(n0 + n) * CC + k0 + cc * 8) = *(uint4*)tmp;
  }
}

// ---------------- prep: background KV (rows L..KVL-1) ----------------
__global__ void k_cvt_bg(const float* __restrict__ Kbg, const float* __restrict__ Vbg,
                         ushort* __restrict__ kb, ushort* __restrict__ vbT, int n4) {
  int i = blockIdx.x * blockDim.x + threadIdx.x;
  if (i >= n4) return;
  int e = i * 4;
  int h = e / (LL * DD);
  int rem = e - h * (LL * DD);
  int kvl = rem >> 6;        // local row 0..4095
  int d0 = rem & 63;         // multiple of 4
  int kv = LL + kvl;         // global kv row
  float4 kf = ((const float4*)Kbg)[i];
  float4 vf = ((const float4*)Vbg)[i];
  {  // K: row-swizzled 16B chunks
    int chunk = d0 >> 3, off = d0 & 7;
    size_t kdst = ((size_t)h * KVL + kv) * 64 + (size_t)(((chunk ^ (kv & 7)) << 3) + off);
    ushort4 ok;
    ok.x = f2bf(ALPHA * kf.x); ok.y = f2bf(ALPHA * kf.y);
    ok.z = f2bf(ALPHA * kf.z); ok.w = f2bf(ALPHA * kf.w);
    *(ushort4*)(kb + kdst) = ok;
  }
  {  // V^T tiles: position-permuted + swizzled
    int tile = kv >> 6, kl = kv & 63;
    int c = vpos(kl);
    size_t vbase = ((size_t)h * 128 + tile) * 4096;
    float vv[4] = {vf.x, vf.y, vf.z, vf.w};
#pragma unroll
    for (int j = 0; j < 4; ++j) {
      int d = d0 + j;
      vbT[vbase + d * 64 + (((c >> 3) ^ (d & 7)) << 3) + (c & 7)] = f2bf(ALPHA * vv[j]);
    }
  }
}

// ---------------- bf16 GEMM: C[M][N] = A[M][K] * BT[N][K]^T ----------------
// MODE 0: Q plain head layout  MODE 1: K row-swizzled
// MODE 2: V^T permuted tiles   MODE 3: fp32 + bias (final)
template <int MODE>
__global__ __launch_bounds__(512) void k_gemm(
    const ushort* __restrict__ A, const ushort* __restrict__ BT,
    ushort* __restrict__ outB, float* __restrict__ outF,
    const float* __restrict__ bias, int M, int Kd, int N, size_t headStride) {
  __shared__ uint4 As4[128 * 8];
  __shared__ uint4 Bs4[64 * 8];
  int tid = threadIdx.x;
  int m0 = blockIdx.x * 128, n0 = blockIdx.y * 64;
  int wid = tid >> 6, lane = tid & 63;
  int wr = wid >> 1, wc = wid & 1;
  int lr = lane & 15, lg = lane >> 4;
  f32x4 acc[2][2] = {};

  for (int kt = 0; kt < Kd; kt += 64) {
    __syncthreads();
    {
      int id = tid;
#pragma unroll
      for (int i = 0; i < 2; ++i, id += 512) {
        int r = id >> 3, cc = id & 7;
        uint4 v = *(const uint4*)(A + (size_t)(m0 + r) * Kd + kt + cc * 8);
        As4[r * 8 + (cc ^ (r & 7))] = v;
      }
      int r = tid >> 3, cc = tid & 7;
      uint4 v = *(const uint4*)(BT + (size_t)(n0 + r) * Kd + kt + cc * 8);
      Bs4[r * 8 + (cc ^ (r & 7))] = v;
    }
    __syncthreads();
#pragma unroll
    for (int k0 = 0; k0 < 2; ++k0) {
      s16x8 a[2], b[2];
#pragma unroll
      for (int i = 0; i < 2; ++i) {
        int r = wr * 32 + i * 16 + lr;
        a[i] = *(const s16x8*)&As4[r * 8 + ((k0 * 4 + lg) ^ (r & 7))];
      }
#pragma unroll
      for (int j = 0; j < 2; ++j) {
        int r = wc * 32 + j * 16 + lr;
        b[j] = *(const s16x8*)&Bs4[r * 8 + ((k0 * 4 + lg) ^ (r & 7))];
      }
#pragma unroll
      for (int i = 0; i < 2; ++i)
#pragma unroll
        for (int j = 0; j < 2; ++j)
          acc[i][j] = __builtin_amdgcn_mfma_f32_16x16x32_bf16(a[i], b[j], acc[i][j], 0, 0, 0);
    }
  }
#pragma unroll
  for (int i = 0; i < 2; ++i)
#pragma unroll
    for (int j = 0; j < 2; ++j)
#pragma unroll
      for (int q = 0; q < 4; ++q) {
        int m = m0 + wr * 32 + i * 16 + lg * 4 + q;
        int n = n0 + wc * 32 + j * 16 + lr;
        float v = acc[i][j][q];
        if (MODE == 3) {
          outF[(size_t)m * N + n] = v + bias[n];
        } else if (MODE == 0) {
          outB[(size_t)(n >> 6) * headStride + (size_t)m * 64 + (n & 63)] = f2bf(v);
        } else if (MODE == 1) {
          int d = n & 63;
          outB[(size_t)(n >> 6) * headStride + (size_t)m * 64 +
               (((d >> 3) ^ (m & 7)) << 3) + (d & 7)] = f2bf(v);
        } else {  // MODE 2: V^T tiles, permuted positions
          int d = n & 63, tile = m >> 6, kl = m & 63;
          int c = vpos(kl);
          outB[((size_t)(n >> 6) * 128 + tile) * 4096 + (size_t)d * 64 +
               (((c >> 3) ^ (d & 7)) << 3) + (c & 7)] = f2bf(v);
        }
      }
}

// ---------------- flash attention (KV-split partials) ----------------
// grid (L/64, H, SPLIT), 256 threads = 4 waves, wave owns 16 q-rows, KVBLK=64.
__global__ __launch_bounds__(256) void k_attn(
    const ushort* __restrict__ qb,    // [H][L][64]
    const ushort* __restrict__ kb,    // [H][KVL][64] row-swizzled
    const ushort* __restrict__ vbT,   // [H][128][4096] V^T tiles
    float* __restrict__ Op,           // [SPLIT][H][L][64] unnormalized
    float* __restrict__ mlb) {        // [SPLIT][H][L][2]
  __shared__ ushort Ks[2][4096];
  __shared__ ushort Vs[2][4096];
  __shared__ ushort Ps[4][1024];

  int tid = threadIdx.x, wid = tid >> 6, lane = tid & 63;
  int lr = lane & 15, lg = lane >> 4;
  int h = blockIdx.y;
  int sp = blockIdx.z;
  int q0 = blockIdx.x * 64 + wid * 16;

  const ushort* qptr = qb + ((size_t)h * LL + q0 + lr) * DD + lg * 8;
  s16x8 qa0 = *(const s16x8*)qptr;
  s16x8 qa1 = *(const s16x8*)(qptr + 32);

  f32x4 o[4] = {};
  float m[4], l4[4];
#pragma unroll
  for (int q = 0; q < 4; ++q) { m[q] = -1e30f; l4[q] = 0.f; }
  const float sc2 = 0.125f * 1.44269504089f;  // (1/sqrt(D)) * log2(e)

  const int t0 = sp * (KVL / SPLIT / 64), NT = KVL / SPLIT / 64;
  const ushort* kh = kb + (size_t)h * KVL * DD + (size_t)t0 * 4096;
  const ushort* vh = vbT + (size_t)h * 128 * 4096 + (size_t)t0 * 4096;
  ushort* Pw = Ps[wid];

  int cur = 0;
#pragma unroll
  for (int i = 0; i < 2; ++i) {  // stage tile 0
    gl16(kh + (i * 256 + tid) * 8, &Ks[0][i * 2048 + wid * 512]);
    gl16(vh + (i * 256 + tid) * 8, &Vs[0][i * 2048 + wid * 512]);
  }

  for (int t = 0; t < NT; ++t) {
    if (t < NT - 1) {
      const ushort* gk = kh + (size_t)(t + 1) * 4096;
      const ushort* gv = vh + (size_t)(t + 1) * 4096;
      int nb = cur ^ 1;
#pragma unroll
      for (int i = 0; i < 2; ++i) {
        gl16(gk + (i * 256 + tid) * 8, &Ks[nb][i * 2048 + wid * 512]);
        gl16(gv + (i * 256 + tid) * 8, &Vs[nb][i * 2048 + wid * 512]);
      }
      asm volatile("s_waitcnt vmcnt(4)" ::: "memory");
    } else {
      asm volatile("s_waitcnt vmcnt(0)" ::: "memory");
    }
    bar();

    const ushort* Kc = Ks[cur];
    const ushort* Vc = Vs[cur];

    // S = Q K^T : 8 MFMA
    f32x4 s[4] = {};
#pragma unroll
    for (int k0 = 0; k0 < 2; ++k0) {
      s16x8 qa = k0 ? qa1 : qa0;
#pragma unroll
      for (int j = 0; j < 4; ++j) {
        int r = j * 16 + lr;
        s16x8 b = *(const s16x8*)&Kc[r * 64 + (((k0 * 4 + lg) ^ (r & 7)) << 3)];
        s[j] = __builtin_amdgcn_mfma_f32_16x16x32_bf16(qa, b, s[j], 0, 0, 0);
      }
    }

    // online softmax; rows = lg*4+q
    float pmax[4];
#pragma unroll
    for (int q = 0; q < 4; ++q)
      pmax[q] = fmaxf(fmaxf(s[0][q], s[1][q]), fmaxf(s[2][q], s[3][q]));
#pragma unroll
    for (int off = 1; off < 16; off <<= 1)
#pragma unroll
      for (int q = 0; q < 4; ++q)
        pmax[q] = fmaxf(pmax[q], __shfl_xor(pmax[q], off));

    float g = -1e30f;
#pragma unroll
    for (int q = 0; q < 4; ++q) g = fmaxf(g, pmax[q] * sc2 - m[q]);
    if (!__all(g <= 8.0f)) {  // defer-max: rescale only on real growth
#pragma unroll
      for (int q = 0; q < 4; ++q) {
        float mn = fmaxf(m[q], pmax[q] * sc2);
        float f = exp2f(m[q] - mn);
        m[q] = mn;
        l4[q] *= f;
#pragma unroll
        for (int j = 0; j < 4; ++j) o[j][q] *= f;
      }
    }

    float p[4][4];
#pragma unroll
    for (int q = 0; q < 4; ++q) {
      float rs = 0.f;
#pragma unroll
      for (int j = 0; j < 4; ++j) {
        float pv = exp2f(s[j][q] * sc2 - m[q]);
        p[j][q] = pv;
        rs += pv;
      }
      l4[q] += rs;  // per-lane partial; reduced at epilogue
    }

    // P -> per-wave LDS: pairs via v_cvt_pk_bf16_f32 (position p=lr*4+j)
#pragma unroll
    for (int q = 0; q < 4; ++q) {
      int r = lg * 4 + q;
      uint w0 = cvtpk(p[0][q], p[1][q]);
      uint w1 = cvtpk(p[2][q], p[3][q]);
      ushort* basep = Pw + r * 64 + (((lr >> 1) ^ (r & 7)) << 3) + ((lr & 1) << 2);
      *(uint*)(basep + 0) = w0;
      *(uint*)(basep + 2) = w1;
    }
    asm volatile("s_waitcnt lgkmcnt(0)" ::: "memory");
    __builtin_amdgcn_sched_barrier(0);

    // O += P V : 8 MFMA (positional contraction; V cols share P's kv permutation)
#pragma unroll
    for (int k0 = 0; k0 < 2; ++k0) {
      s16x8 pa = *(const s16x8*)&Pw[lr * 64 + (((k0 * 4 + lg) ^ (lr & 7)) << 3)];
#pragma unroll
      for (int j = 0; j < 4; ++j) {
        int r = j * 16 + lr;  // d row in V^T
        s16x8 bv = *(const s16x8*)&Vc[r * 64 + (((k0 * 4 + lg) ^ (r & 7)) << 3)];
        o[j] = __builtin_amdgcn_mfma_f32_16x16x32_bf16(pa, bv, o[j], 0, 0, 0);
      }
    }
    bar();
    cur ^= 1;
  }

  // reduce l across the 16 lanes sharing each row
#pragma unroll
  for (int off = 1; off < 16; off <<= 1)
#pragma unroll
    for (int q = 0; q < 4; ++q)
      l4[q] += __shfl_xor(l4[q], off);

  // store unnormalized partials
  size_t rbase = ((size_t)sp * HH + h) * LL;
#pragma unroll
  for (int j = 0; j < 4; ++j)
#pragma unroll
    for (int q = 0; q < 4; ++q) {
      int row = q0 + lg * 4 + q;
      Op[(rbase + row) * 64 + j * 16 + lr] = o[j][q];
    }
  if (lr == 0) {
#pragma unroll
    for (int q = 0; q < 4; ++q) {
      int row = q0 + lg * 4 + q;
      mlb[(rbase + row) * 2 + 0] = m[q];
      mlb[(rbase + row) * 2 + 1] = l4[q];
    }
  }
}

// ---------------- combine partials -> ctx bf16 [L][C] ----------------
__global__ __launch_bounds__(256) void k_comb(
    const float* __restrict__ Op, const float* __restrict__ mlb,
    ushort* __restrict__ ctx) {
  int t = threadIdx.x;
  int h = blockIdx.y;
  int row = blockIdx.x * 64 + (t >> 2);
  int d0 = (t & 3) * 16;

  float ms[SPLIT], ls[SPLIT];
  float M = -1e30f;
#pragma unroll
  for (int s = 0; s < SPLIT; ++s) {
    size_t rb = ((size_t)s * HH + h) * LL + row;
    ms[s] = mlb[rb * 2 + 0];
    ls[s] = mlb[rb * 2 + 1];
    M = fmaxf(M, ms[s]);
  }
  float Lsum = 0.f, w[SPLIT];
#pragma unroll
  for (int s = 0; s < SPLIT; ++s) {
    w[s] = exp2f(ms[s] - M);
    Lsum += ls[s] * w[s];
  }
  float inv = 1.0f / Lsum;

  float acc[16] = {};
#pragma unroll
  for (int s = 0; s < SPLIT; ++s) {
    size_t rb = (((size_t)s * HH + h) * LL + row) * 64 + d0;
#pragma unroll
    for (int i = 0; i < 4; ++i) {
      float4 v = *(const float4*)(Op + rb + i * 4);
      acc[i * 4 + 0] += w[s] * v.x;
      acc[i * 4 + 1] += w[s] * v.y;
      acc[i * 4 + 2] += w[s] * v.z;
      acc[i * 4 + 3] += w[s] * v.w;
    }
  }
  ushort ob[16];
#pragma unroll
  for (int i = 0; i < 16; ++i) ob[i] = f2bf(acc[i] * inv);
  ushort* dst = ctx + (size_t)row * CC + h * 64 + d0;
  *(uint4*)(dst + 0) = *(uint4*)(ob + 0);
  *(uint4*)(dst + 8) = *(uint4*)(ob + 8);
}

extern "C" void kernel_launch(void* const* d_in, const int* in_sizes, int n_in,
                              void* d_out, int out_size, void* d_ws, size_t ws_size,
                              hipStream_t stream) {
  const float* hs  = (const float*)d_in[0];
  const float* Kbg = (const float*)d_in[1];
  const float* Vbg = (const float*)d_in[2];
  const float* Wq  = (const float*)d_in[3];
  const float* Wk  = (const float*)d_in[4];
  const float* Wv  = (const float*)d_in[5];
  const float* Wo  = (const float*)d_in[6];
  const float* bo  = (const float*)d_in[7];
  float* out = (float*)d_out;

  char* p = (char*)d_ws;
  ushort* hs_b = (ushort*)p; p += (size_t)LL * CC * 2;
  ushort* WqT  = (ushort*)p; p += (size_t)CC * CC * 2;
  ushort* WkT  = (ushort*)p; p += (size_t)CC * CC * 2;
  ushort* WvT  = (ushort*)p; p += (size_t)CC * CC * 2;
  ushort* WoT  = (ushort*)p; p += (size_t)CC * CC * 2;
  ushort* qb   = (ushort*)p; p += (size_t)HH * LL * DD * 2;
  ushort* kb   = (ushort*)p; p += (size_t)HH * KVL * DD * 2;
  ushort* vbT  = (ushort*)p; p += (size_t)HH * KVL * DD * 2;
  ushort* ctxb = (ushort*)p; p += (size_t)LL * CC * 2;
  float* Opart = (float*)p;  p += (size_t)SPLIT * HH * LL * DD * 4;
  float* mlb   = (float*)p;  p += (size_t)SPLIT * HH * LL * 2 * 4;

  int n4hs = LL * CC / 4;
  k_cvt_hs<<<(n4hs + 255) / 256, 256, 0, stream>>>(hs, hs_b, n4hs);
  k_wT<<<dim3(CC / 64, CC / 64), 256, 0, stream>>>(Wq, WqT);
  k_wT<<<dim3(CC / 64, CC / 64), 256, 0, stream>>>(Wk, WkT);
  k_wT<<<dim3(CC / 64, CC / 64), 256, 0, stream>>>(Wv, WvT);
  k_wT<<<dim3(CC / 64, CC / 64), 256, 0, stream>>>(Wo, WoT);
  int n4bg = HH * LL * DD / 4;
  k_cvt_bg<<<(n4bg + 255) / 256, 256, 0, stream>>>(Kbg, Vbg, kb, vbT, n4bg);

  k_gemm<0><<<dim3(LL / 128, CC / 64), 512, 0, stream>>>(
      hs_b, WqT, qb, nullptr, nullptr, LL, CC, CC, (size_t)LL * DD);
  k_gemm<1><<<dim3(LL / 128, CC / 64), 512, 0, stream>>>(
      hs_b, WkT, kb, nullptr, nullptr, LL, CC, CC, (size_t)KVL * DD);
  k_gemm<2><<<dim3(LL / 128, CC / 64), 512, 0, stream>>>(
      hs_b, WvT, vbT, nullptr, nullptr, LL, CC, CC, 0);

  k_attn<<<dim3(LL / 64, HH, SPLIT), 256, 0, stream>>>(qb, kb, vbT, Opart, mlb);
  k_comb<<<dim3(LL / 64, HH), 256, 0, stream>>>(Opart, mlb, ctxb);

  k_gemm<3><<<dim3(LL / 128, CC / 64), 512, 0, stream>>>(
      ctxb, WoT, nullptr, out, bo, LL, CC, CC, 0);
}

// Round 4
// 289.306 us; speedup vs baseline: 1.9138x; 1.0701x over previous
//
#include <hip/hip_runtime.h>
#include <stdint.h>

#define HH 10
#define DD 64
#define LL 4096
#define CC 640
#define KVL 8192
#define ALPHA 0.42f
#define SPLIT 2
#define SC2 0.1803368801111204f  // (1/sqrt(64)) * log2(e)

typedef __attribute__((ext_vector_type(8))) short s16x8;
typedef __attribute__((ext_vector_type(4))) float f32x4;

__device__ inline ushort f2bf(float f) {
  uint32_t u = __builtin_bit_cast(uint32_t, f);
  u += 0x7FFFu + ((u >> 16) & 1u);   // RNE
  return (ushort)(u >> 16);
}

__device__ inline uint cvtpk(float lo, float hi) {
  uint r;
  asm("v_cvt_pk_bf16_f32 %0, %1, %2" : "=v"(r) : "v"(lo), "v"(hi));
  return r;
}

__device__ inline void gl16(const ushort* g, ushort* l) {
  __builtin_amdgcn_global_load_lds(
      (const __attribute__((address_space(1))) uint32_t*)g,
      (__attribute__((address_space(3))) uint32_t*)l, 16, 0, 0);
}

__device__ inline void bar() {
  __builtin_amdgcn_sched_barrier(0);
  __builtin_amdgcn_s_barrier();
  __builtin_amdgcn_sched_barrier(0);
}

// V^T tile column position for kv-local row kl (0..63):
// position p holds kv label (p&3)*16 + (p>>2); inverse: p = (kl&15)*4 + (kl>>4)
__device__ inline int vpos(int kl) { return ((kl & 15) << 2) | (kl >> 4); }

// ---------------- prep: hs fp32 -> bf16 ----------------
__global__ void k_cvt_hs(const float* __restrict__ in, ushort* __restrict__ out, int n4) {
  int i = blockIdx.x * blockDim.x + threadIdx.x;
  if (i < n4) {
    float4 v = ((const float4*)in)[i];
    ushort4 o;
    o.x = f2bf(v.x); o.y = f2bf(v.y); o.z = f2bf(v.z); o.w = f2bf(v.w);
    ((ushort4*)out)[i] = o;
  }
}

// ---------------- prep: W [K][N] fp32 -> WT [N][K] bf16 ----------------
__global__ void k_wT(const float* __restrict__ W, ushort* __restrict__ WT) {
  __shared__ ushort t[64][65];
  int k0 = blockIdx.x * 64, n0 = blockIdx.y * 64;
  int tid = threadIdx.x;
#pragma unroll
  for (int i = 0; i < 4; ++i) {
    int id = tid + i * 256;
    int r = id >> 4, c4 = id & 15;
    float4 v = *(const float4*)(W + (size_t)(k0 + r) * CC + n0 + c4 * 4);
    t[r][c4 * 4 + 0] = f2bf(v.x);
    t[r][c4 * 4 + 1] = f2bf(v.y);
    t[r][c4 * 4 + 2] = f2bf(v.z);
    t[r][c4 * 4 + 3] = f2bf(v.w);
  }
  __syncthreads();
#pragma unroll
  for (int i = 0; i < 2; ++i) {
    int id = tid + i * 256;
    int n = id >> 3, cc = id & 7;
    ushort tmp[8];
#pragma unroll
    for (int j = 0; j < 8; ++j) tmp[j] = t[cc * 8 + j][n];
    *(uint4*)(WT + (size_t)(n0 + n) * CC + k0 + cc * 8) = *(uint4*)tmp;
  }
}

// ---------------- prep: background KV (rows L..KVL-1) ----------------
__global__ void k_cvt_bg(const float* __restrict__ Kbg, const float* __restrict__ Vbg,
                         ushort* __restrict__ kb, ushort* __restrict__ vbT, int n4) {
  int i = blockIdx.x * blockDim.x + threadIdx.x;
  if (i >= n4) return;
  int e = i * 4;
  int h = e / (LL * DD);
  int rem = e - h * (LL * DD);
  int kvl = rem >> 6;        // local row 0..4095
  int d0 = rem & 63;         // multiple of 4
  int kv = LL + kvl;         // global kv row
  float4 kf = ((const float4*)Kbg)[i];
  float4 vf = ((const float4*)Vbg)[i];
  {  // K: row-swizzled 16B chunks
    int chunk = d0 >> 3, off = d0 & 7;
    size_t kdst = ((size_t)h * KVL + kv) * 64 + (size_t)(((chunk ^ (kv & 7)) << 3) + off);
    ushort4 ok;
    ok.x = f2bf(ALPHA * kf.x); ok.y = f2bf(ALPHA * kf.y);
    ok.z = f2bf(ALPHA * kf.z); ok.w = f2bf(ALPHA * kf.w);
    *(ushort4*)(kb + kdst) = ok;
  }
  {  // V^T tiles: position-permuted + swizzled
    int tile = kv >> 6, kl = kv & 63;
    int c = vpos(kl);
    size_t vbase = ((size_t)h * 128 + tile) * 4096;
    float vv[4] = {vf.x, vf.y, vf.z, vf.w};
#pragma unroll
    for (int j = 0; j < 4; ++j) {
      int d = d0 + j;
      vbT[vbase + d * 64 + (((c >> 3) ^ (d & 7)) << 3) + (c & 7)] = f2bf(ALPHA * vv[j]);
    }
  }
}

// ---------------- bf16 GEMM: C[M][N] = A[M][K] * BT[N][K]^T ----------------
// MODE 0: Q head layout, scaled by SC2  MODE 1: K row-swizzled
// MODE 2: V^T permuted tiles            MODE 3: fp32 + bias (final)
template <int MODE>
__global__ __launch_bounds__(512) void k_gemm(
    const ushort* __restrict__ A, const ushort* __restrict__ BT,
    ushort* __restrict__ outB, float* __restrict__ outF,
    const float* __restrict__ bias, int M, int Kd, int N, size_t headStride) {
  __shared__ uint4 As4[128 * 8];
  __shared__ uint4 Bs4[64 * 8];
  int tid = threadIdx.x;
  int m0 = blockIdx.x * 128, n0 = blockIdx.y * 64;
  int wid = tid >> 6, lane = tid & 63;
  int wr = wid >> 1, wc = wid & 1;
  int lr = lane & 15, lg = lane >> 4;
  f32x4 acc[2][2] = {};

  for (int kt = 0; kt < Kd; kt += 64) {
    __syncthreads();
    {
      int id = tid;
#pragma unroll
      for (int i = 0; i < 2; ++i, id += 512) {
        int r = id >> 3, cc = id & 7;
        uint4 v = *(const uint4*)(A + (size_t)(m0 + r) * Kd + kt + cc * 8);
        As4[r * 8 + (cc ^ (r & 7))] = v;
      }
      int r = tid >> 3, cc = tid & 7;
      uint4 v = *(const uint4*)(BT + (size_t)(n0 + r) * Kd + kt + cc * 8);
      Bs4[r * 8 + (cc ^ (r & 7))] = v;
    }
    __syncthreads();
#pragma unroll
    for (int k0 = 0; k0 < 2; ++k0) {
      s16x8 a[2], b[2];
#pragma unroll
      for (int i = 0; i < 2; ++i) {
        int r = wr * 32 + i * 16 + lr;
        a[i] = *(const s16x8*)&As4[r * 8 + ((k0 * 4 + lg) ^ (r & 7))];
      }
#pragma unroll
      for (int j = 0; j < 2; ++j) {
        int r = wc * 32 + j * 16 + lr;
        b[j] = *(const s16x8*)&Bs4[r * 8 + ((k0 * 4 + lg) ^ (r & 7))];
      }
#pragma unroll
      for (int i = 0; i < 2; ++i)
#pragma unroll
        for (int j = 0; j < 2; ++j)
          acc[i][j] = __builtin_amdgcn_mfma_f32_16x16x32_bf16(a[i], b[j], acc[i][j], 0, 0, 0);
    }
  }
#pragma unroll
  for (int i = 0; i < 2; ++i)
#pragma unroll
    for (int j = 0; j < 2; ++j)
#pragma unroll
      for (int q = 0; q < 4; ++q) {
        int m = m0 + wr * 32 + i * 16 + lg * 4 + q;
        int n = n0 + wc * 32 + j * 16 + lr;
        float v = acc[i][j][q];
        if (MODE == 3) {
          outF[(size_t)m * N + n] = v + bias[n];
        } else if (MODE == 0) {
          outB[(size_t)(n >> 6) * headStride + (size_t)m * 64 + (n & 63)] = f2bf(v * SC2);
        } else if (MODE == 1) {
          int d = n & 63;
          outB[(size_t)(n >> 6) * headStride + (size_t)m * 64 +
               (((d >> 3) ^ (m & 7)) << 3) + (d & 7)] = f2bf(v);
        } else {  // MODE 2: V^T tiles, permuted positions
          int d = n & 63, tile = m >> 6, kl = m & 63;
          int c = vpos(kl);
          outB[((size_t)(n >> 6) * 128 + tile) * 4096 + (size_t)d * 64 +
               (((c >> 3) ^ (d & 7)) << 3) + (c & 7)] = f2bf(v);
        }
      }
}

// ---------------- flash attention (KV-split, static max m=0) ----------------
// grid (L/128, H, SPLIT), 256 threads = 4 waves, wave owns 32 q-rows, KVBLK=64.
__global__ __launch_bounds__(256) void k_attn(
    const ushort* __restrict__ qb,    // [H][L][64], pre-scaled by SC2
    const ushort* __restrict__ kb,    // [H][KVL][64] row-swizzled
    const ushort* __restrict__ vbT,   // [H][128][4096] V^T tiles
    float* __restrict__ Op,           // [SPLIT][H][L][64] unnormalized
    float* __restrict__ lb) {         // [SPLIT][H][L] row sums
  __shared__ ushort Ks[2][4096];
  __shared__ ushort Vs[2][4096];
  __shared__ ushort Ps[4][2048];      // per-wave 32x64 P tile

  int tid = threadIdx.x, wid = tid >> 6, lane = tid & 63;
  int lr = lane & 15, lg = lane >> 4;
  int h = blockIdx.y;
  int sp = blockIdx.z;
  int q0 = blockIdx.x * 128 + wid * 32;

  // Q fragments: 2 row-blocks x 2 k-chunks
  s16x8 qa[2][2];
#pragma unroll
  for (int i = 0; i < 2; ++i) {
    const ushort* qptr = qb + ((size_t)h * LL + q0 + i * 16 + lr) * DD + lg * 8;
    qa[i][0] = *(const s16x8*)qptr;
    qa[i][1] = *(const s16x8*)(qptr + 32);
  }

  f32x4 o[2][4] = {};
  f32x4 l4[2] = {};

  const int t0 = sp * (KVL / SPLIT / 64), NT = KVL / SPLIT / 64;
  const ushort* kh = kb + (size_t)h * KVL * DD + (size_t)t0 * 4096;
  const ushort* vh = vbT + (size_t)h * 128 * 4096 + (size_t)t0 * 4096;
  ushort* Pw = Ps[wid];

  int cur = 0;
#pragma unroll
  for (int i = 0; i < 2; ++i) {  // stage tile 0
    gl16(kh + (i * 256 + tid) * 8, &Ks[0][i * 2048 + wid * 512]);
    gl16(vh + (i * 256 + tid) * 8, &Vs[0][i * 2048 + wid * 512]);
  }

  for (int t = 0; t < NT; ++t) {
    if (t < NT - 1) {
      const ushort* gk = kh + (size_t)(t + 1) * 4096;
      const ushort* gv = vh + (size_t)(t + 1) * 4096;
      int nb = cur ^ 1;
#pragma unroll
      for (int i = 0; i < 2; ++i) {
        gl16(gk + (i * 256 + tid) * 8, &Ks[nb][i * 2048 + wid * 512]);
        gl16(gv + (i * 256 + tid) * 8, &Vs[nb][i * 2048 + wid * 512]);
      }
      asm volatile("s_waitcnt vmcnt(4)" ::: "memory");
    } else {
      asm volatile("s_waitcnt vmcnt(0)" ::: "memory");
    }
    bar();

    const ushort* Kc = Ks[cur];
    const ushort* Vc = Vs[cur];

    // S = Q K^T : 16 MFMA (2 row-blocks x 4 col-blocks x 2 k-chunks)
    f32x4 s[2][4] = {};
#pragma unroll
    for (int k0 = 0; k0 < 2; ++k0) {
#pragma unroll
      for (int j = 0; j < 4; ++j) {
        int r = j * 16 + lr;
        s16x8 b = *(const s16x8*)&Kc[r * 64 + (((k0 * 4 + lg) ^ (r & 7)) << 3)];
        s[0][j] = __builtin_amdgcn_mfma_f32_16x16x32_bf16(qa[0][k0], b, s[0][j], 0, 0, 0);
        s[1][j] = __builtin_amdgcn_mfma_f32_16x16x32_bf16(qa[1][k0], b, s[1][j], 0, 0, 0);
      }
    }

    // P = exp2(S) (Q pre-scaled; static max), accumulate row-sum partials
#pragma unroll
    for (int i = 0; i < 2; ++i) {
#pragma unroll
      for (int j = 0; j < 4; ++j)
#pragma unroll
        for (int q = 0; q < 4; ++q)
          s[i][j][q] = exp2f(s[i][j][q]);
      l4[i] += (s[i][0] + s[i][1]) + (s[i][2] + s[i][3]);
    }

    // P -> per-wave LDS: ds_write_b64 per (i,q), position p = lr*4+j
#pragma unroll
    for (int i = 0; i < 2; ++i)
#pragma unroll
      for (int q = 0; q < 4; ++q) {
        int r = i * 16 + lg * 4 + q;
        uint2 w;
        w.x = cvtpk(s[i][0][q], s[i][1][q]);
        w.y = cvtpk(s[i][2][q], s[i][3][q]);
        *(uint2*)(Pw + r * 64 + (((lr >> 1) ^ (r & 7)) << 3) + ((lr & 1) << 2)) = w;
      }
    asm volatile("s_waitcnt lgkmcnt(0)" ::: "memory");
    __builtin_amdgcn_sched_barrier(0);

    // O += P V : 16 MFMA (positional contraction; V shares P's kv permutation)
#pragma unroll
    for (int k0 = 0; k0 < 2; ++k0) {
      s16x8 pa0 = *(const s16x8*)&Pw[lr * 64 + (((k0 * 4 + lg) ^ (lr & 7)) << 3)];
      s16x8 pa1 = *(const s16x8*)&Pw[(16 + lr) * 64 + (((k0 * 4 + lg) ^ (lr & 7)) << 3)];
#pragma unroll
      for (int j = 0; j < 4; ++j) {
        int r = j * 16 + lr;  // d row in V^T
        s16x8 bv = *(const s16x8*)&Vc[r * 64 + (((k0 * 4 + lg) ^ (r & 7)) << 3)];
        o[0][j] = __builtin_amdgcn_mfma_f32_16x16x32_bf16(pa0, bv, o[0][j], 0, 0, 0);
        o[1][j] = __builtin_amdgcn_mfma_f32_16x16x32_bf16(pa1, bv, o[1][j], 0, 0, 0);
      }
    }
    bar();
    cur ^= 1;
  }

  // reduce row-sum partials across the 16 lanes sharing each row
#pragma unroll
  for (int off = 1; off < 16; off <<= 1)
#pragma unroll
    for (int i = 0; i < 2; ++i)
#pragma unroll
      for (int q = 0; q < 4; ++q)
        l4[i][q] += __shfl_xor(l4[i][q], off);

  // store unnormalized partials
  size_t rbase = ((size_t)sp * HH + h) * LL;
#pragma unroll
  for (int i = 0; i < 2; ++i)
#pragma unroll
    for (int j = 0; j < 4; ++j)
#pragma unroll
      for (int q = 0; q < 4; ++q) {
        int row = q0 + i * 16 + lg * 4 + q;
        Op[(rbase + row) * 64 + j * 16 + lr] = o[i][j][q];
      }
  if (lr == 0) {
#pragma unroll
    for (int i = 0; i < 2; ++i)
#pragma unroll
      for (int q = 0; q < 4; ++q)
        lb[rbase + q0 + i * 16 + lg * 4 + q] = l4[i][q];
  }
}

// ---------------- combine partials -> ctx bf16 [L][C] ----------------
__global__ __launch_bounds__(256) void k_comb(
    const float* __restrict__ Op, const float* __restrict__ lb,
    ushort* __restrict__ ctx) {
  int t = threadIdx.x;
  int h = blockIdx.y;
  int row = blockIdx.x * 64 + (t >> 2);
  int d0 = (t & 3) * 16;

  float Lsum = 0.f;
#pragma unroll
  for (int s = 0; s < SPLIT; ++s)
    Lsum += lb[((size_t)s * HH + h) * LL + row];
  float inv = 1.0f / Lsum;

  float acc[16] = {};
#pragma unroll
  for (int s = 0; s < SPLIT; ++s) {
    size_t rb = (((size_t)s * HH + h) * LL + row) * 64 + d0;
#pragma unroll
    for (int i = 0; i < 4; ++i) {
      float4 v = *(const float4*)(Op + rb + i * 4);
      acc[i * 4 + 0] += v.x;
      acc[i * 4 + 1] += v.y;
      acc[i * 4 + 2] += v.z;
      acc[i * 4 + 3] += v.w;
    }
  }
  ushort ob[16];
#pragma unroll
  for (int i = 0; i < 16; ++i) ob[i] = f2bf(acc[i] * inv);
  ushort* dst = ctx + (size_t)row * CC + h * 64 + d0;
  *(uint4*)(dst + 0) = *(uint4*)(ob + 0);
  *(uint4*)(dst + 8) = *(uint4*)(ob + 8);
}

extern "C" void kernel_launch(void* const* d_in, const int* in_sizes, int n_in,
                              void* d_out, int out_size, void* d_ws, size_t ws_size,
                              hipStream_t stream) {
  const float* hs  = (const float*)d_in[0];
  const float* Kbg = (const float*)d_in[1];
  const float* Vbg = (const float*)d_in[2];
  const float* Wq  = (const float*)d_in[3];
  const float* Wk  = (const float*)d_in[4];
  const float* Wv  = (const float*)d_in[5];
  const float* Wo  = (const float*)d_in[6];
  const float* bo  = (const float*)d_in[7];
  float* out = (float*)d_out;

  char* p = (char*)d_ws;
  ushort* hs_b = (ushort*)p; p += (size_t)LL * CC * 2;
  ushort* WqT  = (ushort*)p; p += (size_t)CC * CC * 2;
  ushort* WkT  = (ushort*)p; p += (size_t)CC * CC * 2;
  ushort* WvT  = (ushort*)p; p += (size_t)CC * CC * 2;
  ushort* WoT  = (ushort*)p; p += (size_t)CC * CC * 2;
  ushort* qb   = (ushort*)p; p += (size_t)HH * LL * DD * 2;
  ushort* kb   = (ushort*)p; p += (size_t)HH * KVL * DD * 2;
  ushort* vbT  = (ushort*)p; p += (size_t)HH * KVL * DD * 2;
  ushort* ctxb = (ushort*)p; p += (size_t)LL * CC * 2;
  float* Opart = (float*)p;  p += (size_t)SPLIT * HH * LL * DD * 4;
  float* lb    = (float*)p;  p += (size_t)SPLIT * HH * LL * 4;

  int n4hs = LL * CC / 4;
  k_cvt_hs<<<(n4hs + 255) / 256, 256, 0, stream>>>(hs, hs_b, n4hs);
  k_wT<<<dim3(CC / 64, CC / 64), 256, 0, stream>>>(Wq, WqT);
  k_wT<<<dim3(CC / 64, CC / 64), 256, 0, stream>>>(Wk, WkT);
  k_wT<<<dim3(CC / 64, CC / 64), 256, 0, stream>>>(Wv, WvT);
  k_wT<<<dim3(CC / 64, CC / 64), 256, 0, stream>>>(Wo, WoT);
  int n4bg = HH * LL * DD / 4;
  k_cvt_bg<<<(n4bg + 255) / 256, 256, 0, stream>>>(Kbg, Vbg, kb, vbT, n4bg);

  k_gemm<0><<<dim3(LL / 128, CC / 64), 512, 0, stream>>>(
      hs_b, WqT, qb, nullptr, nullptr, LL, CC, CC, (size_t)LL * DD);
  k_gemm<1><<<dim3(LL / 128, CC / 64), 512, 0, stream>>>(
      hs_b, WkT, kb, nullptr, nullptr, LL, CC, CC, (size_t)KVL * DD);
  k_gemm<2><<<dim3(LL / 128, CC / 64), 512, 0, stream>>>(
      hs_b, WvT, vbT, nullptr, nullptr, LL, CC, CC, 0);

  k_attn<<<dim3(LL / 128, HH, SPLIT), 256, 0, stream>>>(qb, kb, vbT, Opart, lb);
  k_comb<<<dim3(LL / 64, HH), 256, 0, stream>>>(Opart, lb, ctxb);

  k_gemm<3><<<dim3(LL / 128, CC / 64), 512, 0, stream>>>(
      ctxb, WoT, nullptr, out, bo, LL, CC, CC, 0);
}

// Round 5
// 256.616 us; speedup vs baseline: 2.1576x; 1.1274x over previous
//
#include <hip/hip_runtime.h>
#include <stdint.h>

#define HH 10
#define DD 64
#define LL 4096
#define CC 640
#define KVL 8192
#define ALPHA 0.42f
#define SPLIT 4
#define SC2 0.1803368801111204f  // (1/sqrt(64)) * log2(e)

typedef __attribute__((ext_vector_type(8))) short s16x8;
typedef __attribute__((ext_vector_type(4))) float f32x4;

__device__ inline ushort f2bf(float f) {
  uint32_t u = __builtin_bit_cast(uint32_t, f);
  u += 0x7FFFu + ((u >> 16) & 1u);   // RNE
  return (ushort)(u >> 16);
}

__device__ inline uint cvtpk(float lo, float hi) {
  uint r;
  asm("v_cvt_pk_bf16_f32 %0, %1, %2" : "=v"(r) : "v"(lo), "v"(hi));
  return r;
}

__device__ inline void gl16(const ushort* g, ushort* l) {
  __builtin_amdgcn_global_load_lds(
      (const __attribute__((address_space(1))) uint32_t*)g,
      (__attribute__((address_space(3))) uint32_t*)l, 16, 0, 0);
}

__device__ inline void bar() {
  __builtin_amdgcn_sched_barrier(0);
  __builtin_amdgcn_s_barrier();
  __builtin_amdgcn_sched_barrier(0);
}

// V^T tile column position for kv-local row kl (0..63):
// position p holds kv label (p&3)*16 + (p>>2); inverse: p = (kl&15)*4 + (kl>>4)
__device__ inline int vpos(int kl) { return ((kl & 15) << 2) | (kl >> 4); }

// ---------------- prep: hs fp32 -> bf16 ----------------
__global__ void k_cvt_hs(const float* __restrict__ in, ushort* __restrict__ out, int n4) {
  int i = blockIdx.x * blockDim.x + threadIdx.x;
  if (i < n4) {
    float4 v = ((const float4*)in)[i];
    ushort4 o;
    o.x = f2bf(v.x); o.y = f2bf(v.y); o.z = f2bf(v.z); o.w = f2bf(v.w);
    ((ushort4*)out)[i] = o;
  }
}

// ---------------- prep: W [K][N] fp32 -> WT [N][K] bf16 ----------------
__global__ void k_wT(const float* __restrict__ W, ushort* __restrict__ WT) {
  __shared__ ushort t[64][65];
  int k0 = blockIdx.x * 64, n0 = blockIdx.y * 64;
  int tid = threadIdx.x;
#pragma unroll
  for (int i = 0; i < 4; ++i) {
    int id = tid + i * 256;
    int r = id >> 4, c4 = id & 15;
    float4 v = *(const float4*)(W + (size_t)(k0 + r) * CC + n0 + c4 * 4);
    t[r][c4 * 4 + 0] = f2bf(v.x);
    t[r][c4 * 4 + 1] = f2bf(v.y);
    t[r][c4 * 4 + 2] = f2bf(v.z);
    t[r][c4 * 4 + 3] = f2bf(v.w);
  }
  __syncthreads();
#pragma unroll
  for (int i = 0; i < 2; ++i) {
    int id = tid + i * 256;
    int n = id >> 3, cc = id & 7;
    ushort tmp[8];
#pragma unroll
    for (int j = 0; j < 8; ++j) tmp[j] = t[cc * 8 + j][n];
    *(uint4*)(WT + (size_t)(n0 + n) * CC + k0 + cc * 8) = *(uint4*)tmp;
  }
}

// ---------------- prep: background KV (rows L..KVL-1) ----------------
__global__ void k_cvt_bg(const float* __restrict__ Kbg, const float* __restrict__ Vbg,
                         ushort* __restrict__ kb, ushort* __restrict__ vbT, int n4) {
  int i = blockIdx.x * blockDim.x + threadIdx.x;
  if (i >= n4) return;
  int e = i * 4;
  int h = e / (LL * DD);
  int rem = e - h * (LL * DD);
  int kvl = rem >> 6;        // local row 0..4095
  int d0 = rem & 63;         // multiple of 4
  int kv = LL + kvl;         // global kv row
  float4 kf = ((const float4*)Kbg)[i];
  float4 vf = ((const float4*)Vbg)[i];
  {  // K: row-swizzled 16B chunks
    int chunk = d0 >> 3, off = d0 & 7;
    size_t kdst = ((size_t)h * KVL + kv) * 64 + (size_t)(((chunk ^ (kv & 7)) << 3) + off);
    ushort4 ok;
    ok.x = f2bf(ALPHA * kf.x); ok.y = f2bf(ALPHA * kf.y);
    ok.z = f2bf(ALPHA * kf.z); ok.w = f2bf(ALPHA * kf.w);
    *(ushort4*)(kb + kdst) = ok;
  }
  {  // V^T tiles: position-permuted + swizzled
    int tile = kv >> 6, kl = kv & 63;
    int c = vpos(kl);
    size_t vbase = ((size_t)h * 128 + tile) * 4096;
    float vv[4] = {vf.x, vf.y, vf.z, vf.w};
#pragma unroll
    for (int j = 0; j < 4; ++j) {
      int d = d0 + j;
      vbT[vbase + d * 64 + (((c >> 3) ^ (d & 7)) << 3) + (c & 7)] = f2bf(ALPHA * vv[j]);
    }
  }
}

// ---------------- bf16 GEMM: C[M][N] = A[M][K] * BT[N][K]^T ----------------
// MODE 0: Q head layout, scaled by SC2  MODE 1: K row-swizzled
// MODE 2: V^T permuted tiles            MODE 3: fp32 + bias (final)
template <int MODE>
__global__ __launch_bounds__(512) void k_gemm(
    const ushort* __restrict__ A, const ushort* __restrict__ BT,
    ushort* __restrict__ outB, float* __restrict__ outF,
    const float* __restrict__ bias, int M, int Kd, int N, size_t headStride) {
  __shared__ uint4 As4[128 * 8];
  __shared__ uint4 Bs4[64 * 8];
  int tid = threadIdx.x;
  int m0 = blockIdx.x * 128, n0 = blockIdx.y * 64;
  int wid = tid >> 6, lane = tid & 63;
  int wr = wid >> 1, wc = wid & 1;
  int lr = lane & 15, lg = lane >> 4;
  f32x4 acc[2][2] = {};

  for (int kt = 0; kt < Kd; kt += 64) {
    __syncthreads();
    {
      int id = tid;
#pragma unroll
      for (int i = 0; i < 2; ++i, id += 512) {
        int r = id >> 3, cc = id & 7;
        uint4 v = *(const uint4*)(A + (size_t)(m0 + r) * Kd + kt + cc * 8);
        As4[r * 8 + (cc ^ (r & 7))] = v;
      }
      int r = tid >> 3, cc = tid & 7;
      uint4 v = *(const uint4*)(BT + (size_t)(n0 + r) * Kd + kt + cc * 8);
      Bs4[r * 8 + (cc ^ (r & 7))] = v;
    }
    __syncthreads();
#pragma unroll
    for (int k0 = 0; k0 < 2; ++k0) {
      s16x8 a[2], b[2];
#pragma unroll
      for (int i = 0; i < 2; ++i) {
        int r = wr * 32 + i * 16 + lr;
        a[i] = *(const s16x8*)&As4[r * 8 + ((k0 * 4 + lg) ^ (r & 7))];
      }
#pragma unroll
      for (int j = 0; j < 2; ++j) {
        int r = wc * 32 + j * 16 + lr;
        b[j] = *(const s16x8*)&Bs4[r * 8 + ((k0 * 4 + lg) ^ (r & 7))];
      }
#pragma unroll
      for (int i = 0; i < 2; ++i)
#pragma unroll
        for (int j = 0; j < 2; ++j)
          acc[i][j] = __builtin_amdgcn_mfma_f32_16x16x32_bf16(a[i], b[j], acc[i][j], 0, 0, 0);
    }
  }
#pragma unroll
  for (int i = 0; i < 2; ++i)
#pragma unroll
    for (int j = 0; j < 2; ++j)
#pragma unroll
      for (int q = 0; q < 4; ++q) {
        int m = m0 + wr * 32 + i * 16 + lg * 4 + q;
        int n = n0 + wc * 32 + j * 16 + lr;
        float v = acc[i][j][q];
        if (MODE == 3) {
          outF[(size_t)m * N + n] = v + bias[n];
        } else if (MODE == 0) {
          outB[(size_t)(n >> 6) * headStride + (size_t)m * 64 + (n & 63)] = f2bf(v * SC2);
        } else if (MODE == 1) {
          int d = n & 63;
          outB[(size_t)(n >> 6) * headStride + (size_t)m * 64 +
               (((d >> 3) ^ (m & 7)) << 3) + (d & 7)] = f2bf(v);
        } else {  // MODE 2: V^T tiles, permuted positions
          int d = n & 63, tile = m >> 6, kl = m & 63;
          int c = vpos(kl);
          outB[((size_t)(n >> 6) * 128 + tile) * 4096 + (size_t)d * 64 +
               (((c >> 3) ^ (d & 7)) << 3) + (c & 7)] = f2bf(v);
        }
      }
}

// ---------------- flash attention (KV-split, static max m=0) ----------------
// grid (L/128, H, SPLIT), 256 threads = 4 waves, wave owns 32 q-rows, KVBLK=64.
__global__ __launch_bounds__(256) void k_attn(
    const ushort* __restrict__ qb,    // [H][L][64], pre-scaled by SC2
    const ushort* __restrict__ kb,    // [H][KVL][64] row-swizzled
    const ushort* __restrict__ vbT,   // [H][128][4096] V^T tiles
    float* __restrict__ Op,           // [SPLIT][H][L][64] unnormalized
    float* __restrict__ lb) {         // [SPLIT][H][L] row sums
  __shared__ ushort Ks[2][4096];
  __shared__ ushort Vs[2][4096];
  __shared__ ushort Ps[4][2048];      // per-wave 32x64 P tile

  int tid = threadIdx.x, wid = tid >> 6, lane = tid & 63;
  int lr = lane & 15, lg = lane >> 4;
  int h = blockIdx.y;
  int sp = blockIdx.z;
  int q0 = blockIdx.x * 128 + wid * 32;

  // Q fragments: 2 row-blocks x 2 k-chunks
  s16x8 qa[2][2];
#pragma unroll
  for (int i = 0; i < 2; ++i) {
    const ushort* qptr = qb + ((size_t)h * LL + q0 + i * 16 + lr) * DD + lg * 8;
    qa[i][0] = *(const s16x8*)qptr;
    qa[i][1] = *(const s16x8*)(qptr + 32);
  }

  f32x4 o[2][4] = {};
  f32x4 l4[2] = {};

  const int t0 = sp * (KVL / SPLIT / 64), NT = KVL / SPLIT / 64;
  const ushort* kh = kb + (size_t)h * KVL * DD + (size_t)t0 * 4096;
  const ushort* vh = vbT + (size_t)h * 128 * 4096 + (size_t)t0 * 4096;
  ushort* Pw = Ps[wid];

  int cur = 0;
#pragma unroll
  for (int i = 0; i < 2; ++i) {  // stage tile 0
    gl16(kh + (i * 256 + tid) * 8, &Ks[0][i * 2048 + wid * 512]);
    gl16(vh + (i * 256 + tid) * 8, &Vs[0][i * 2048 + wid * 512]);
  }

  for (int t = 0; t < NT; ++t) {
    if (t < NT - 1) {
      const ushort* gk = kh + (size_t)(t + 1) * 4096;
      const ushort* gv = vh + (size_t)(t + 1) * 4096;
      int nb = cur ^ 1;
#pragma unroll
      for (int i = 0; i < 2; ++i) {
        gl16(gk + (i * 256 + tid) * 8, &Ks[nb][i * 2048 + wid * 512]);
        gl16(gv + (i * 256 + tid) * 8, &Vs[nb][i * 2048 + wid * 512]);
      }
      asm volatile("s_waitcnt vmcnt(4)" ::: "memory");
    } else {
      asm volatile("s_waitcnt vmcnt(0)" ::: "memory");
    }
    bar();

    const ushort* Kc = Ks[cur];
    const ushort* Vc = Vs[cur];

    // S = Q K^T : 16 MFMA (2 row-blocks x 4 col-blocks x 2 k-chunks)
    f32x4 s[2][4] = {};
    __builtin_amdgcn_s_setprio(1);
#pragma unroll
    for (int k0 = 0; k0 < 2; ++k0) {
#pragma unroll
      for (int j = 0; j < 4; ++j) {
        int r = j * 16 + lr;
        s16x8 b = *(const s16x8*)&Kc[r * 64 + (((k0 * 4 + lg) ^ (r & 7)) << 3)];
        s[0][j] = __builtin_amdgcn_mfma_f32_16x16x32_bf16(qa[0][k0], b, s[0][j], 0, 0, 0);
        s[1][j] = __builtin_amdgcn_mfma_f32_16x16x32_bf16(qa[1][k0], b, s[1][j], 0, 0, 0);
      }
    }
    __builtin_amdgcn_s_setprio(0);

    // P = exp2(S) (Q pre-scaled; static max), accumulate row-sum partials
#pragma unroll
    for (int i = 0; i < 2; ++i) {
#pragma unroll
      for (int j = 0; j < 4; ++j)
#pragma unroll
        for (int q = 0; q < 4; ++q)
          s[i][j][q] = exp2f(s[i][j][q]);
      l4[i] += (s[i][0] + s[i][1]) + (s[i][2] + s[i][3]);
    }

    // P -> per-wave LDS: ds_write_b64 per (i,q), position p = lr*4+j
#pragma unroll
    for (int i = 0; i < 2; ++i)
#pragma unroll
      for (int q = 0; q < 4; ++q) {
        int r = i * 16 + lg * 4 + q;
        uint2 w;
        w.x = cvtpk(s[i][0][q], s[i][1][q]);
        w.y = cvtpk(s[i][2][q], s[i][3][q]);
        *(uint2*)(Pw + r * 64 + (((lr >> 1) ^ (r & 7)) << 3) + ((lr & 1) << 2)) = w;
      }
    asm volatile("s_waitcnt lgkmcnt(0)" ::: "memory");
    __builtin_amdgcn_sched_barrier(0);

    // O += P V : 16 MFMA (positional contraction; V shares P's kv permutation)
    __builtin_amdgcn_s_setprio(1);
#pragma unroll
    for (int k0 = 0; k0 < 2; ++k0) {
      s16x8 pa0 = *(const s16x8*)&Pw[lr * 64 + (((k0 * 4 + lg) ^ (lr & 7)) << 3)];
      s16x8 pa1 = *(const s16x8*)&Pw[(16 + lr) * 64 + (((k0 * 4 + lg) ^ (lr & 7)) << 3)];
#pragma unroll
      for (int j = 0; j < 4; ++j) {
        int r = j * 16 + lr;  // d row in V^T
        s16x8 bv = *(const s16x8*)&Vc[r * 64 + (((k0 * 4 + lg) ^ (r & 7)) << 3)];
        o[0][j] = __builtin_amdgcn_mfma_f32_16x16x32_bf16(pa0, bv, o[0][j], 0, 0, 0);
        o[1][j] = __builtin_amdgcn_mfma_f32_16x16x32_bf16(pa1, bv, o[1][j], 0, 0, 0);
      }
    }
    __builtin_amdgcn_s_setprio(0);
    bar();
    cur ^= 1;
  }

  // reduce row-sum partials across the 16 lanes sharing each row
#pragma unroll
  for (int off = 1; off < 16; off <<= 1)
#pragma unroll
    for (int i = 0; i < 2; ++i)
#pragma unroll
      for (int q = 0; q < 4; ++q)
        l4[i][q] += __shfl_xor(l4[i][q], off);

  // store unnormalized partials
  size_t rbase = ((size_t)sp * HH + h) * LL;
#pragma unroll
  for (int i = 0; i < 2; ++i)
#pragma unroll
    for (int j = 0; j < 4; ++j)
#pragma unroll
      for (int q = 0; q < 4; ++q) {
        int row = q0 + i * 16 + lg * 4 + q;
        Op[(rbase + row) * 64 + j * 16 + lr] = o[i][j][q];
      }
  if (lr == 0) {
#pragma unroll
    for (int i = 0; i < 2; ++i)
#pragma unroll
      for (int q = 0; q < 4; ++q)
        lb[rbase + q0 + i * 16 + lg * 4 + q] = l4[i][q];
  }
}

// ---------------- combine partials -> ctx bf16 [L][C] ----------------
__global__ __launch_bounds__(256) void k_comb(
    const float* __restrict__ Op, const float* __restrict__ lb,
    ushort* __restrict__ ctx) {
  int t = threadIdx.x;
  int h = blockIdx.y;
  int row = blockIdx.x * 64 + (t >> 2);
  int d0 = (t & 3) * 16;

  float Lsum = 0.f;
#pragma unroll
  for (int s = 0; s < SPLIT; ++s)
    Lsum += lb[((size_t)s * HH + h) * LL + row];
  float inv = 1.0f / Lsum;

  float acc[16] = {};
#pragma unroll
  for (int s = 0; s < SPLIT; ++s) {
    size_t rb = (((size_t)s * HH + h) * LL + row) * 64 + d0;
#pragma unroll
    for (int i = 0; i < 4; ++i) {
      float4 v = *(const float4*)(Op + rb + i * 4);
      acc[i * 4 + 0] += v.x;
      acc[i * 4 + 1] += v.y;
      acc[i * 4 + 2] += v.z;
      acc[i * 4 + 3] += v.w;
    }
  }
  ushort ob[16];
#pragma unroll
  for (int i = 0; i < 16; ++i) ob[i] = f2bf(acc[i] * inv);
  ushort* dst = ctx + (size_t)row * CC + h * 64 + d0;
  *(uint4*)(dst + 0) = *(uint4*)(ob + 0);
  *(uint4*)(dst + 8) = *(uint4*)(ob + 8);
}

extern "C" void kernel_launch(void* const* d_in, const int* in_sizes, int n_in,
                              void* d_out, int out_size, void* d_ws, size_t ws_size,
                              hipStream_t stream) {
  const float* hs  = (const float*)d_in[0];
  const float* Kbg = (const float*)d_in[1];
  const float* Vbg = (const float*)d_in[2];
  const float* Wq  = (const float*)d_in[3];
  const float* Wk  = (const float*)d_in[4];
  const float* Wv  = (const float*)d_in[5];
  const float* Wo  = (const float*)d_in[6];
  const float* bo  = (const float*)d_in[7];
  float* out = (float*)d_out;

  char* p = (char*)d_ws;
  ushort* hs_b = (ushort*)p; p += (size_t)LL * CC * 2;
  ushort* WqT  = (ushort*)p; p += (size_t)CC * CC * 2;
  ushort* WkT  = (ushort*)p; p += (size_t)CC * CC * 2;
  ushort* WvT  = (ushort*)p; p += (size_t)CC * CC * 2;
  ushort* WoT  = (ushort*)p; p += (size_t)CC * CC * 2;
  ushort* qb   = (ushort*)p; p += (size_t)HH * LL * DD * 2;
  ushort* kb   = (ushort*)p; p += (size_t)HH * KVL * DD * 2;
  ushort* vbT  = (ushort*)p; p += (size_t)HH * KVL * DD * 2;
  ushort* ctxb = (ushort*)p; p += (size_t)LL * CC * 2;
  float* Opart = (float*)p;  p += (size_t)SPLIT * HH * LL * DD * 4;
  float* lb    = (float*)p;  p += (size_t)SPLIT * HH * LL * 4;

  int n4hs = LL * CC / 4;
  k_cvt_hs<<<(n4hs + 255) / 256, 256, 0, stream>>>(hs, hs_b, n4hs);
  k_wT<<<dim3(CC / 64, CC / 64), 256, 0, stream>>>(Wq, WqT);
  k_wT<<<dim3(CC / 64, CC / 64), 256, 0, stream>>>(Wk, WkT);
  k_wT<<<dim3(CC / 64, CC / 64), 256, 0, stream>>>(Wv, WvT);
  k_wT<<<dim3(CC / 64, CC / 64), 256, 0, stream>>>(Wo, WoT);
  int n4bg = HH * LL * DD / 4;
  k_cvt_bg<<<(n4bg + 255) / 256, 256, 0, stream>>>(Kbg, Vbg, kb, vbT, n4bg);

  k_gemm<0><<<dim3(LL / 128, CC / 64), 512, 0, stream>>>(
      hs_b, WqT, qb, nullptr, nullptr, LL, CC, CC, (size_t)LL * DD);
  k_gemm<1><<<dim3(LL / 128, CC / 64), 512, 0, stream>>>(
      hs_b, WkT, kb, nullptr, nullptr, LL, CC, CC, (size_t)KVL * DD);
  k_gemm<2><<<dim3(LL / 128, CC / 64), 512, 0, stream>>>(
      hs_b, WvT, vbT, nullptr, nullptr, LL, CC, CC, 0);

  k_attn<<<dim3(LL / 128, HH, SPLIT), 256, 0, stream>>>(qb, kb, vbT, Opart, lb);
  k_comb<<<dim3(LL / 64, HH), 256, 0, stream>>>(Opart, lb, ctxb);

  k_gemm<3><<<dim3(LL / 128, CC / 64), 512, 0, stream>>>(
      ctxb, WoT, nullptr, out, bo, LL, CC, CC, 0);
}

// Round 6
// 199.355 us; speedup vs baseline: 2.7773x; 1.2872x over previous
//
#include <hip/hip_runtime.h>
#include <stdint.h>

#define HH 10
#define DD 64
#define LL 4096
#define CC 640
#define KVL 8192
#define ALPHA 0.42f
#define SPLIT 4
#define SC2 0.1803368801111204f  // (1/sqrt(64)) * log2(e)

typedef __attribute__((ext_vector_type(8))) short s16x8;
typedef __attribute__((ext_vector_type(4))) float f32x4;

__device__ inline ushort f2bf(float f) {
  uint32_t u = __builtin_bit_cast(uint32_t, f);
  u += 0x7FFFu + ((u >> 16) & 1u);   // RNE
  return (ushort)(u >> 16);
}

__device__ inline uint cvtpk(float lo, float hi) {
  uint r;
  asm("v_cvt_pk_bf16_f32 %0, %1, %2" : "=v"(r) : "v"(lo), "v"(hi));
  return r;
}

__device__ inline void gl16(const ushort* g, ushort* l) {
  __builtin_amdgcn_global_load_lds(
      (const __attribute__((address_space(1))) uint32_t*)g,
      (__attribute__((address_space(3))) uint32_t*)l, 16, 0, 0);
}

__device__ inline void bar() {
  __builtin_amdgcn_sched_barrier(0);
  __builtin_amdgcn_s_barrier();
  __builtin_amdgcn_sched_barrier(0);
}

// V^T tile column position for kv-local row kl (0..63), matching the
// register layout of the swapped-QK^T P fragment (see k_attn):
// A-slot s=8*lg+m (within 32-block k0) must hold kv = 32*k0+16*(m>>2)+4*lg+(m&3).
// Inverse: p = (kl&32) | ((kl&12)<<1) | ((kl&16)>>2) | (kl&3)
__device__ inline int vpos(int kl) {
  return (kl & 32) | ((kl & 12) << 1) | ((kl & 16) >> 2) | (kl & 3);
}

// ---------------- prep: hs fp32 -> bf16 ----------------
__global__ void k_cvt_hs(const float* __restrict__ in, ushort* __restrict__ out, int n4) {
  int i = blockIdx.x * blockDim.x + threadIdx.x;
  if (i < n4) {
    float4 v = ((const float4*)in)[i];
    ushort4 o;
    o.x = f2bf(v.x); o.y = f2bf(v.y); o.z = f2bf(v.z); o.w = f2bf(v.w);
    ((ushort4*)out)[i] = o;
  }
}

// ---------------- prep: W [K][N] fp32 -> WT [N][K] bf16 ----------------
__global__ void k_wT(const float* __restrict__ W, ushort* __restrict__ WT) {
  __shared__ ushort t[64][65];
  int k0 = blockIdx.x * 64, n0 = blockIdx.y * 64;
  int tid = threadIdx.x;
#pragma unroll
  for (int i = 0; i < 4; ++i) {
    int id = tid + i * 256;
    int r = id >> 4, c4 = id & 15;
    float4 v = *(const float4*)(W + (size_t)(k0 + r) * CC + n0 + c4 * 4);
    t[r][c4 * 4 + 0] = f2bf(v.x);
    t[r][c4 * 4 + 1] = f2bf(v.y);
    t[r][c4 * 4 + 2] = f2bf(v.z);
    t[r][c4 * 4 + 3] = f2bf(v.w);
  }
  __syncthreads();
#pragma unroll
  for (int i = 0; i < 2; ++i) {
    int id = tid + i * 256;
    int n = id >> 3, cc = id & 7;
    ushort tmp[8];
#pragma unroll
    for (int j = 0; j < 8; ++j) tmp[j] = t[cc * 8 + j][n];
    *(uint4*)(WT + (size_t)(n0 + n) * CC + k0 + cc * 8) = *(uint4*)tmp;
  }
}

// ---------------- prep: background KV (rows L..KVL-1) ----------------
__global__ void k_cvt_bg(const float* __restrict__ Kbg, const float* __restrict__ Vbg,
                         ushort* __restrict__ kb, ushort* __restrict__ vbT, int n4) {
  int i = blockIdx.x * blockDim.x + threadIdx.x;
  if (i >= n4) return;
  int e = i * 4;
  int h = e / (LL * DD);
  int rem = e - h * (LL * DD);
  int kvl = rem >> 6;        // local row 0..4095
  int d0 = rem & 63;         // multiple of 4
  int kv = LL + kvl;         // global kv row
  float4 kf = ((const float4*)Kbg)[i];
  float4 vf = ((const float4*)Vbg)[i];
  {  // K: row-swizzled 16B chunks
    int chunk = d0 >> 3, off = d0 & 7;
    size_t kdst = ((size_t)h * KVL + kv) * 64 + (size_t)(((chunk ^ (kv & 7)) << 3) + off);
    ushort4 ok;
    ok.x = f2bf(ALPHA * kf.x); ok.y = f2bf(ALPHA * kf.y);
    ok.z = f2bf(ALPHA * kf.z); ok.w = f2bf(ALPHA * kf.w);
    *(ushort4*)(kb + kdst) = ok;
  }
  {  // V^T tiles: position-permuted + swizzled
    int tile = kv >> 6, kl = kv & 63;
    int c = vpos(kl);
    size_t vbase = ((size_t)h * 128 + tile) * 4096;
    float vv[4] = {vf.x, vf.y, vf.z, vf.w};
#pragma unroll
    for (int j = 0; j < 4; ++j) {
      int d = d0 + j;
      vbT[vbase + d * 64 + (((c >> 3) ^ (d & 7)) << 3) + (c & 7)] = f2bf(ALPHA * vv[j]);
    }
  }
}

// ---------------- bf16 GEMM: C[M][N] = A[M][K] * BT[N][K]^T ----------------
// MODE 0: Q head layout, scaled by SC2  MODE 1: K row-swizzled
// MODE 2: V^T permuted tiles            MODE 3: fp32 + bias (final)
template <int MODE>
__global__ __launch_bounds__(512) void k_gemm(
    const ushort* __restrict__ A, const ushort* __restrict__ BT,
    ushort* __restrict__ outB, float* __restrict__ outF,
    const float* __restrict__ bias, int M, int Kd, int N, size_t headStride) {
  __shared__ uint4 As4[128 * 8];
  __shared__ uint4 Bs4[64 * 8];
  int tid = threadIdx.x;
  int m0 = blockIdx.x * 128, n0 = blockIdx.y * 64;
  int wid = tid >> 6, lane = tid & 63;
  int wr = wid >> 1, wc = wid & 1;
  int lr = lane & 15, lg = lane >> 4;
  f32x4 acc[2][2] = {};

  for (int kt = 0; kt < Kd; kt += 64) {
    __syncthreads();
    {
      int id = tid;
#pragma unroll
      for (int i = 0; i < 2; ++i, id += 512) {
        int r = id >> 3, cc = id & 7;
        uint4 v = *(const uint4*)(A + (size_t)(m0 + r) * Kd + kt + cc * 8);
        As4[r * 8 + (cc ^ (r & 7))] = v;
      }
      int r = tid >> 3, cc = tid & 7;
      uint4 v = *(const uint4*)(BT + (size_t)(n0 + r) * Kd + kt + cc * 8);
      Bs4[r * 8 + (cc ^ (r & 7))] = v;
    }
    __syncthreads();
#pragma unroll
    for (int k0 = 0; k0 < 2; ++k0) {
      s16x8 a[2], b[2];
#pragma unroll
      for (int i = 0; i < 2; ++i) {
        int r = wr * 32 + i * 16 + lr;
        a[i] = *(const s16x8*)&As4[r * 8 + ((k0 * 4 + lg) ^ (r & 7))];
      }
#pragma unroll
      for (int j = 0; j < 2; ++j) {
        int r = wc * 32 + j * 16 + lr;
        b[j] = *(const s16x8*)&Bs4[r * 8 + ((k0 * 4 + lg) ^ (r & 7))];
      }
#pragma unroll
      for (int i = 0; i < 2; ++i)
#pragma unroll
        for (int j = 0; j < 2; ++j)
          acc[i][j] = __builtin_amdgcn_mfma_f32_16x16x32_bf16(a[i], b[j], acc[i][j], 0, 0, 0);
    }
  }
#pragma unroll
  for (int i = 0; i < 2; ++i)
#pragma unroll
    for (int j = 0; j < 2; ++j)
#pragma unroll
      for (int q = 0; q < 4; ++q) {
        int m = m0 + wr * 32 + i * 16 + lg * 4 + q;
        int n = n0 + wc * 32 + j * 16 + lr;
        float v = acc[i][j][q];
        if (MODE == 3) {
          outF[(size_t)m * N + n] = v + bias[n];
        } else if (MODE == 0) {
          outB[(size_t)(n >> 6) * headStride + (size_t)m * 64 + (n & 63)] = f2bf(v * SC2);
        } else if (MODE == 1) {
          int d = n & 63;
          outB[(size_t)(n >> 6) * headStride + (size_t)m * 64 +
               (((d >> 3) ^ (m & 7)) << 3) + (d & 7)] = f2bf(v);
        } else {  // MODE 2: V^T tiles, permuted positions
          int d = n & 63, tile = m >> 6, kl = m & 63;
          int c = vpos(kl);
          outB[((size_t)(n >> 6) * 128 + tile) * 4096 + (size_t)d * 64 +
               (((c >> 3) ^ (d & 7)) << 3) + (c & 7)] = f2bf(v);
        }
      }
}

// ---------------- flash attention (KV-split, static max, in-register P) ----------------
// grid (L/128, H, SPLIT), 256 threads = 4 waves, wave owns 32 q-rows, KVBLK=64.
// Swapped QK^T: S^T = mfma(K_frag, Q_frag) -> lane holds q-row = lane&15 and
// 16 kv values; after exp2 + cvt_pk the packed words ARE the PV A-fragment
// (V^T producer permutes kv columns by vpos to match). P never touches LDS.
__global__ __launch_bounds__(256, 4) void k_attn(
    const ushort* __restrict__ qb,    // [H][L][64], pre-scaled by SC2
    const ushort* __restrict__ kb,    // [H][KVL][64] row-swizzled
    const ushort* __restrict__ vbT,   // [H][128][4096] V^T permuted tiles
    float* __restrict__ Op,           // [SPLIT][H][L][64] unnormalized
    float* __restrict__ lb) {         // [SPLIT][H][L] row sums
  __shared__ ushort Ks[2][4096];
  __shared__ ushort Vs[2][4096];

  int tid = threadIdx.x, wid = tid >> 6, lane = tid & 63;
  int lr = lane & 15, lg = lane >> 4;
  int h = blockIdx.y;
  int sp = blockIdx.z;
  int q0 = blockIdx.x * 128 + wid * 32;

  // Q fragments: 2 row-blocks x 2 k-chunks (B-operand layout: lane -> Q[row=lr][d=lg*8..])
  s16x8 qa[2][2];
#pragma unroll
  for (int i = 0; i < 2; ++i) {
    const ushort* qptr = qb + ((size_t)h * LL + q0 + i * 16 + lr) * DD + lg * 8;
    qa[i][0] = *(const s16x8*)qptr;
    qa[i][1] = *(const s16x8*)(qptr + 32);
  }

  f32x4 o[2][4] = {};
  f32x4 l4[2] = {};

  const int t0 = sp * (KVL / SPLIT / 64), NT = KVL / SPLIT / 64;
  const ushort* kh = kb + (size_t)h * KVL * DD + (size_t)t0 * 4096;
  const ushort* vh = vbT + (size_t)h * 128 * 4096 + (size_t)t0 * 4096;

  // prologue: stage tile 0, wait, sync
#pragma unroll
  for (int i = 0; i < 2; ++i) {
    gl16(kh + (i * 256 + tid) * 8, &Ks[0][i * 2048 + wid * 512]);
    gl16(vh + (i * 256 + tid) * 8, &Vs[0][i * 2048 + wid * 512]);
  }
  asm volatile("s_waitcnt vmcnt(0)" ::: "memory");
  bar();

  for (int t = 0; t < NT; ++t) {
    // stage next tile (other buffer); current buffer reads all precede the
    // end-of-iter barrier, next iteration's staging follows it -> race-free
    if (t < NT - 1) {
      const ushort* gk = kh + (size_t)(t + 1) * 4096;
      const ushort* gv = vh + (size_t)(t + 1) * 4096;
      int nb = (t + 1) & 1;
#pragma unroll
      for (int i = 0; i < 2; ++i) {
        gl16(gk + (i * 256 + tid) * 8, &Ks[nb][i * 2048 + wid * 512]);
        gl16(gv + (i * 256 + tid) * 8, &Vs[nb][i * 2048 + wid * 512]);
      }
    }

    const ushort* Kc = Ks[t & 1];
    const ushort* Vc = Vs[t & 1];

    // S^T = K Q^T : 16 MFMA. Lane (lg,lr), reg r of s[i][j]:
    //   S[q = q0+i*16+lr][kv = t*64 + j*16 + lg*4 + r]
    f32x4 s[2][4] = {};
    __builtin_amdgcn_s_setprio(1);
#pragma unroll
    for (int k0 = 0; k0 < 2; ++k0) {
#pragma unroll
      for (int j = 0; j < 4; ++j) {
        int r = j * 16 + lr;
        s16x8 kf = *(const s16x8*)&Kc[r * 64 + (((k0 * 4 + lg) ^ (r & 7)) << 3)];
        s[0][j] = __builtin_amdgcn_mfma_f32_16x16x32_bf16(kf, qa[0][k0], s[0][j], 0, 0, 0);
        s[1][j] = __builtin_amdgcn_mfma_f32_16x16x32_bf16(kf, qa[1][k0], s[1][j], 0, 0, 0);
      }
    }
    __builtin_amdgcn_s_setprio(0);

    // P = exp2(S) (Q pre-scaled, static max), per-lane row-sum partials,
    // pack to bf16 pairs in-register
    uint w[2][4][2];
#pragma unroll
    for (int i = 0; i < 2; ++i) {
#pragma unroll
      for (int j = 0; j < 4; ++j)
#pragma unroll
        for (int q = 0; q < 4; ++q)
          s[i][j][q] = exp2f(s[i][j][q]);
      l4[i] += (s[i][0] + s[i][1]) + (s[i][2] + s[i][3]);
#pragma unroll
      for (int j = 0; j < 4; ++j) {
        w[i][j][0] = cvtpk(s[i][j][0], s[i][j][1]);
        w[i][j][1] = cvtpk(s[i][j][2], s[i][j][3]);
      }
    }

    // O += P V : 16 MFMA, P fragment assembled from lane-local words
    __builtin_amdgcn_s_setprio(1);
#pragma unroll
    for (int k0 = 0; k0 < 2; ++k0) {
      uint4 u0, u1;
      u0.x = w[0][2 * k0][0]; u0.y = w[0][2 * k0][1];
      u0.z = w[0][2 * k0 + 1][0]; u0.w = w[0][2 * k0 + 1][1];
      u1.x = w[1][2 * k0][0]; u1.y = w[1][2 * k0][1];
      u1.z = w[1][2 * k0 + 1][0]; u1.w = w[1][2 * k0 + 1][1];
      s16x8 pa0 = __builtin_bit_cast(s16x8, u0);
      s16x8 pa1 = __builtin_bit_cast(s16x8, u1);
#pragma unroll
      for (int j = 0; j < 4; ++j) {
        int r = j * 16 + lr;  // d row in V^T
        s16x8 bv = *(const s16x8*)&Vc[r * 64 + (((k0 * 4 + lg) ^ (r & 7)) << 3)];
        o[0][j] = __builtin_amdgcn_mfma_f32_16x16x32_bf16(pa0, bv, o[0][j], 0, 0, 0);
        o[1][j] = __builtin_amdgcn_mfma_f32_16x16x32_bf16(pa1, bv, o[1][j], 0, 0, 0);
      }
    }
    __builtin_amdgcn_s_setprio(0);

    asm volatile("s_waitcnt vmcnt(0)" ::: "memory");  // next tile landed (issued ~full phase ago)
    bar();
  }

  // row sums: lane's partials all belong to row q = i*16+lr; reduce over lg
  float lt[2];
#pragma unroll
  for (int i = 0; i < 2; ++i) {
    lt[i] = (l4[i][0] + l4[i][1]) + (l4[i][2] + l4[i][3]);
    lt[i] += __shfl_xor(lt[i], 16);
    lt[i] += __shfl_xor(lt[i], 32);
  }

  // store unnormalized partials: row = q0 + i*16 + lg*4 + q, col = j*16 + lr
  size_t rbase = ((size_t)sp * HH + h) * LL;
#pragma unroll
  for (int i = 0; i < 2; ++i)
#pragma unroll
    for (int j = 0; j < 4; ++j)
#pragma unroll
      for (int q = 0; q < 4; ++q) {
        int row = q0 + i * 16 + lg * 4 + q;
        Op[(rbase + row) * 64 + j * 16 + lr] = o[i][j][q];
      }
  if (lane < 16) {
#pragma unroll
    for (int i = 0; i < 2; ++i)
      lb[rbase + q0 + i * 16 + lane] = lt[i];
  }
}

// ---------------- combine partials -> ctx bf16 [L][C] ----------------
__global__ __launch_bounds__(256) void k_comb(
    const float* __restrict__ Op, const float* __restrict__ lb,
    ushort* __restrict__ ctx) {
  int t = threadIdx.x;
  int h = blockIdx.y;
  int row = blockIdx.x * 64 + (t >> 2);
  int d0 = (t & 3) * 16;

  float Lsum = 0.f;
#pragma unroll
  for (int s = 0; s < SPLIT; ++s)
    Lsum += lb[((size_t)s * HH + h) * LL + row];
  float inv = 1.0f / Lsum;

  float acc[16] = {};
#pragma unroll
  for (int s = 0; s < SPLIT; ++s) {
    size_t rb = (((size_t)s * HH + h) * LL + row) * 64 + d0;
#pragma unroll
    for (int i = 0; i < 4; ++i) {
      float4 v = *(const float4*)(Op + rb + i * 4);
      acc[i * 4 + 0] += v.x;
      acc[i * 4 + 1] += v.y;
      acc[i * 4 + 2] += v.z;
      acc[i * 4 + 3] += v.w;
    }
  }
  ushort ob[16];
#pragma unroll
  for (int i = 0; i < 16; ++i) ob[i] = f2bf(acc[i] * inv);
  ushort* dst = ctx + (size_t)row * CC + h * 64 + d0;
  *(uint4*)(dst + 0) = *(uint4*)(ob + 0);
  *(uint4*)(dst + 8) = *(uint4*)(ob + 8);
}

extern "C" void kernel_launch(void* const* d_in, const int* in_sizes, int n_in,
                              void* d_out, int out_size, void* d_ws, size_t ws_size,
                              hipStream_t stream) {
  const float* hs  = (const float*)d_in[0];
  const float* Kbg = (const float*)d_in[1];
  const float* Vbg = (const float*)d_in[2];
  const float* Wq  = (const float*)d_in[3];
  const float* Wk  = (const float*)d_in[4];
  const float* Wv  = (const float*)d_in[5];
  const float* Wo  = (const float*)d_in[6];
  const float* bo  = (const float*)d_in[7];
  float* out = (float*)d_out;

  char* p = (char*)d_ws;
  ushort* hs_b = (ushort*)p; p += (size_t)LL * CC * 2;
  ushort* WqT  = (ushort*)p; p += (size_t)CC * CC * 2;
  ushort* WkT  = (ushort*)p; p += (size_t)CC * CC * 2;
  ushort* WvT  = (ushort*)p; p += (size_t)CC * CC * 2;
  ushort* WoT  = (ushort*)p; p += (size_t)CC * CC * 2;
  ushort* qb   = (ushort*)p; p += (size_t)HH * LL * DD * 2;
  ushort* kb   = (ushort*)p; p += (size_t)HH * KVL * DD * 2;
  ushort* vbT  = (ushort*)p; p += (size_t)HH * KVL * DD * 2;
  ushort* ctxb = (ushort*)p; p += (size_t)LL * CC * 2;
  float* Opart = (float*)p;  p += (size_t)SPLIT * HH * LL * DD * 4;
  float* lb    = (float*)p;  p += (size_t)SPLIT * HH * LL * 4;

  int n4hs = LL * CC / 4;
  k_cvt_hs<<<(n4hs + 255) / 256, 256, 0, stream>>>(hs, hs_b, n4hs);
  k_wT<<<dim3(CC / 64, CC / 64), 256, 0, stream>>>(Wq, WqT);
  k_wT<<<dim3(CC / 64, CC / 64), 256, 0, stream>>>(Wk, WkT);
  k_wT<<<dim3(CC / 64, CC / 64), 256, 0, stream>>>(Wv, WvT);
  k_wT<<<dim3(CC / 64, CC / 64), 256, 0, stream>>>(Wo, WoT);
  int n4bg = HH * LL * DD / 4;
  k_cvt_bg<<<(n4bg + 255) / 256, 256, 0, stream>>>(Kbg, Vbg, kb, vbT, n4bg);

  k_gemm<0><<<dim3(LL / 128, CC / 64), 512, 0, stream>>>(
      hs_b, WqT, qb, nullptr, nullptr, LL, CC, CC, (size_t)LL * DD);
  k_gemm<1><<<dim3(LL / 128, CC / 64), 512, 0, stream>>>(
      hs_b, WkT, kb, nullptr, nullptr, LL, CC, CC, (size_t)KVL * DD);
  k_gemm<2><<<dim3(LL / 128, CC / 64), 512, 0, stream>>>(
      hs_b, WvT, vbT, nullptr, nullptr, LL, CC, CC, 0);

  k_attn<<<dim3(LL / 128, HH, SPLIT), 256, 0, stream>>>(qb, kb, vbT, Opart, lb);
  k_comb<<<dim3(LL / 64, HH), 256, 0, stream>>>(Opart, lb, ctxb);

  k_gemm<3><<<dim3(LL / 128, CC / 64), 512, 0, stream>>>(
      ctxb, WoT, nullptr, out, bo, LL, CC, CC, 0);
}